// Round 13
// baseline (273.443 us; speedup 1.0000x reference)
//
#include <hip/hip_runtime.h>
#include <math.h>

// ---------------------------------------------------------------------------
// ConvAttention (B=32, T1=1600, T2=400, n_mel=80, n_text=512, n_att=80)
// Round 13: conv1_both back to 256x256 tiles (r10 geometry) now that the
//   XCD imbalance that sank r10 is fixed: per-range bijective swizzles
//   (key 204 tiles: 26x4+25x4 per XCD; q 201: 26+25x7). T2 chunk swizzle
//   retained; vmcnt(4); wave tile 128co x 64n (32 MFMA per barrier pair).
// ---------------------------------------------------------------------------

typedef __attribute__((ext_vector_type(8))) short bf16x8;
typedef __attribute__((ext_vector_type(4))) float f32x4;

static __device__ __forceinline__ unsigned short f2bf(float f) {
    union { float f; unsigned u; } v; v.f = f;
    unsigned r = v.u + 0x7FFF + ((v.u >> 16) & 1);
    return (unsigned short)(r >> 16);
}
static __device__ __forceinline__ float bf2f(unsigned short h) {
    union { unsigned u; float f; } v; v.u = ((unsigned)h) << 16;
    return v.f;
}

#define GLOAD16(g, s) __builtin_amdgcn_global_load_lds( \
    (const __attribute__((address_space(1))) void*)(g), \
    (__attribute__((address_space(3))) void*)(s), 16, 0, 0)

// ---------------- kernel 1: all prep ----------------
static __device__ __forceinline__ void fill_w(
    const float* __restrict__ w, unsigned short* __restrict__ dst, int rem,
    int Cout, int Cin, int KTAP, int CoutAlloc, int CinPad)
{
    int d  = rem / (CoutAlloc * CinPad);
    int r2 = rem - d * (CoutAlloc * CinPad);
    int co = r2 / CinPad, ci = r2 - co * CinPad;
    float v = (co < Cout && ci < Cin) ? w[((size_t)co * Cin + ci) * KTAP + d] : 0.f;
    dst[rem] = f2bf(v);
}

#define S0 1572864       // Wk1 3*1024*512
#define S1 (S0+131072)   // Wk2 128*1024
#define S2 (S1+73728)    // Wq1 3*256*96
#define S3 (S2+20480)    // Wq2 128*160
#define S4 (S3+12288)    // Wq3 128*96
#define S5 (S4+66560)    // Xk tail 130*512
#define S6 (S5+12480)    // Xq tail 130*96
#define NKB 6656         // 13*16*32 key transpose blocks
#define NQB 4896         // 51*3*32  query transpose blocks
#define NFB ((S6+255)/256)

static __device__ __forceinline__ void transpose_body(
    const float* __restrict__ in, unsigned short* __restrict__ Xt,
    int C, int CinPad, int T, int Trow,
    int bx, int by, int bz, float s[32][33])
{
    int ci0 = by * 32, tr0 = bx * 32;
    int tx = threadIdx.x & 31, ty = threadIdx.x >> 5;
#pragma unroll
    for (int i = 0; i < 4; i++) {
        int c = ci0 + ty + 8 * i;
        int t_in = tr0 + tx - 1;
        float v = (c < C && t_in >= 0 && t_in < T)
                    ? in[((size_t)bz * C + c) * T + t_in] : 0.f;
        s[ty + 8 * i][tx] = v;
    }
    __syncthreads();
#pragma unroll
    for (int i = 0; i < 4; i++) {
        int tr = tr0 + ty + 8 * i;
        if (tr < Trow)
            Xt[((size_t)bz * Trow + tr) * CinPad + ci0 + tx] = f2bf(s[tx][ty + 8 * i]);
    }
}

__global__ __launch_bounds__(256) void prep_all(
    const float* __restrict__ keys, const float* __restrict__ queries,
    const float* __restrict__ kw1, const float* __restrict__ kw2,
    const float* __restrict__ qw1, const float* __restrict__ qw2,
    const float* __restrict__ qw3,
    unsigned short* __restrict__ Xk, unsigned short* __restrict__ Xq,
    unsigned short* __restrict__ Wk1, unsigned short* __restrict__ Wk2,
    unsigned short* __restrict__ Wq1, unsigned short* __restrict__ Wq2,
    unsigned short* __restrict__ Wq3)
{
    __shared__ float s[32][33];
    int bxg = blockIdx.x;
    if (bxg < NKB) {
        int x = bxg % 13, y = (bxg / 13) & 15, z = bxg / (13 * 16);
        transpose_body(keys, Xk, 512, 512, 400, 404, x, y, z, s);
    } else if (bxg < NKB + NQB) {
        int b2 = bxg - NKB;
        int x = b2 % 51, y = (b2 / 51) % 3, z = b2 / 153;
        transpose_body(queries, Xq, 80, 96, 1600, 1604, x, y, z, s);
    } else {
        int idx = (bxg - NKB - NQB) * 256 + threadIdx.x;
        if (idx < S0)      fill_w(kw1, Wk1, idx,       1024, 512, 3, 1024, 512);
        else if (idx < S1) fill_w(kw2, Wk2, idx - S0,  80, 1024, 1, 128, 1024);
        else if (idx < S2) fill_w(qw1, Wq1, idx - S1,  160, 80, 3, 256, 96);
        else if (idx < S3) fill_w(qw2, Wq2, idx - S2,  80, 160, 1, 128, 160);
        else if (idx < S4) fill_w(qw3, Wq3, idx - S3,  80, 80, 1, 128, 96);
        else if (idx < S5) Xk[(size_t)12928 * 512 + (idx - S4)] = 0;
        else if (idx < S6) Xq[(size_t)51328 * 96  + (idx - S5)] = 0;
    }
}

// ---------------- kernel 2: both 3-tap convs (256x256, counted vmcnt) -------
// key: 204 tiles (4 co x 51 n), q: 201 tiles (1 co x 201 n). 405 blocks.
// Per-range XCD-bijective swizzles (balanced); T2 chunk swizzle; vmcnt(4).
// Wave tile 128co x 64n -> 32 MFMA per barrier pair; 2 blocks/CU at 64KB LDS.
__global__ __launch_bounds__(512) void conv1_both(
    const unsigned short* __restrict__ Wk1, const unsigned short* __restrict__ Xk,
    const float* __restrict__ kb1, unsigned short* __restrict__ K1t,
    const unsigned short* __restrict__ Wq1, const unsigned short* __restrict__ Xq,
    const float* __restrict__ qb1, unsigned short* __restrict__ Q1t)
{
    constexpr int TRW = 264; // epilogue strip row stride (256 + 8)
    __shared__ unsigned short lds[32768]; // 2 bufs x (A[256][32] + B[256][32])

    const int tid  = threadIdx.x;
    const int lane = tid & 63;
    const int wid  = tid >> 6;
    const int wm   = wid >> 2;   // 0..1 : co half (128 rows)
    const int wn   = wid & 3;    // 0..3 : n quarter (64 rows)

    const int bid = blockIdx.x;
    const unsigned short* Wbf; const unsigned short* Xt;
    const float* bias; unsigned short* out;
    int CinPad, CoutAlloc, Cout, Trow, Tout, OutStride, nCo, Nvalid, wgid;
    if (bid < 204) {
        // key range: 204 = 8*25.5 -> chunks 26,26,26,26,25,25,25,25 (m204)
        int xcd = bid & 7, ix = bid >> 3;
        wgid = (xcd < 4 ? xcd * 26 : 4 * 26 + (xcd - 4) * 25) + ix;
        Wbf = Wk1; Xt = Xk; bias = kb1; out = K1t;
        CinPad = 512; CoutAlloc = 1024; Cout = 1024; Trow = 404; Tout = 400;
        OutStride = 1024; nCo = 4; Nvalid = 12928;
    } else {
        // q range: 201 -> chunks 26,25x7 (m204)
        int b2 = bid - 204;
        int xcd = b2 & 7, ix = b2 >> 3;
        wgid = (xcd < 1 ? 0 : 26 + (xcd - 1) * 25) + ix;
        Wbf = Wq1; Xt = Xq; bias = qb1; out = Q1t;
        CinPad = 96; CoutAlloc = 256; Cout = 160; Trow = 1604; Tout = 1600;
        OutStride = 160; nCo = 1; Nvalid = 51328;
    }
    const int co0 = (wgid % nCo) * 256;
    const int n0  = (wgid / nCo) * 256;

    const int lr = lane >> 2;        // staging sub-row 0..15
    const int fr = lane & 15;
    // T2 chunk swizzle: LDS slot (row, c) holds global chunk c ^ ((row&15)>>1 & 3).
    // row&15 == lr on staging (rows wid*32+lr, wid*32+16+lr) and == fr on read
    // (rows w*64|128 + k*16 + fr) -> the XOR term is loop-invariant.
    const int lc = (((lane & 3) ^ ((lr >> 1) & 3)) * 8);
    const int ko = (((lane >> 4) ^ ((fr >> 1) & 3)) * 8);

    const int nKc   = CinPad >> 5;
    const int nIter = 3 * nKc;

    f32x4 a4[8][4] = {};

    int scc = 0, sd = 0;
#define STAGE(B)                                                                  \
    {                                                                             \
        const unsigned short* asrc =                                              \
            Wbf + ((size_t)sd * CoutAlloc + co0 + wid * 32 + lr) * CinPad + scc * 32 + lc; \
        const unsigned short* bsrc =                                              \
            Xt + ((size_t)(n0 + sd) + wid * 32 + lr) * CinPad + scc * 32 + lc;    \
        unsigned short* Ab = lds + (B) * 16384;                                   \
        unsigned short* Bb = Ab + 8192;                                           \
        GLOAD16(asrc,                       &Ab[wid * 1024]);                     \
        GLOAD16(asrc + (size_t)16 * CinPad, &Ab[wid * 1024 + 512]);               \
        GLOAD16(bsrc,                       &Bb[wid * 1024]);                     \
        GLOAD16(bsrc + (size_t)16 * CinPad, &Bb[wid * 1024 + 512]);               \
        scc++; if (scc == nKc) { scc = 0; sd++; }                                 \
    }

#define COMPUTE(B)                                                                \
    {                                                                             \
        const unsigned short* Ab = lds + (B) * 16384;                             \
        const unsigned short* Bb = Ab + 8192;                                     \
        bf16x8 af[8], bfr[4];                                                     \
        _Pragma("unroll")                                                         \
        for (int mi = 0; mi < 8; mi++)                                            \
            af[mi] = *(const bf16x8*)&Ab[(wm * 128 + mi * 16 + fr) * 32 + ko];    \
        _Pragma("unroll")                                                         \
        for (int ni = 0; ni < 4; ni++)                                            \
            bfr[ni] = *(const bf16x8*)&Bb[(wn * 64 + ni * 16 + fr) * 32 + ko];    \
        _Pragma("unroll")                                                         \
        for (int mi = 0; mi < 8; mi++)                                            \
            _Pragma("unroll")                                                     \
            for (int ni = 0; ni < 4; ni++)                                        \
                a4[mi][ni] = __builtin_amdgcn_mfma_f32_16x16x32_bf16(             \
                    af[mi], bfr[ni], a4[mi][ni], 0, 0, 0);                        \
    }

    STAGE(0);
    STAGE(1);

    for (int t = 0; t < nIter; t++) {
        if (t < nIter - 1)
            asm volatile("s_waitcnt vmcnt(4)" ::: "memory"); // tile t done; t+1 in flight
        else
            asm volatile("s_waitcnt vmcnt(0)" ::: "memory");
        __builtin_amdgcn_s_barrier();
        COMPUTE(t & 1);
        __builtin_amdgcn_sched_barrier(0);
        __builtin_amdgcn_s_barrier();
        if (t + 2 < nIter) STAGE(t & 1);
    }
#undef STAGE
#undef COMPUTE

    __syncthreads();

    // four-pass epilogue: strip p = n-rows [p*64, p*64+64)
    int cw = OutStride - co0; if (cw > 256) cw = 256;
#pragma unroll
    for (int p = 0; p < 4; p++) {
        if (wn == p) {
#pragma unroll
            for (int mi = 0; mi < 8; mi++) {
                int col = wm * 128 + mi * 16 + (lane >> 4) * 4;
#pragma unroll
                for (int ni = 0; ni < 4; ni++) {
                    int row = ni * 16 + fr;
                    unsigned short pk[4];
#pragma unroll
                    for (int r = 0; r < 4; r++) {
                        int co = co0 + col + r;
                        float v = 0.f;
                        if (co < Cout) v = fmaxf(a4[mi][ni][r] + bias[co], 0.f);
                        pk[r] = f2bf(v);
                    }
                    *(unsigned long long*)&lds[row * TRW + col] = *(unsigned long long*)pk;
                }
            }
        }
        __syncthreads();
        int row = tid >> 3;          // 0..63
        int c0  = (tid & 7) * 32;    // 32-col chunk
        int n   = n0 + p * 64 + row;
        if (n < Nvalid) {
            int b = n / Trow;
            int t = n - b * Trow;
            if (t < Tout) {
                unsigned short* dst = out + ((size_t)b * Tout + t) * OutStride + co0;
#pragma unroll
                for (int c = c0; c < c0 + 32; c += 8)
                    if (c < cw)
                        *(bf16x8*)&dst[c] = *(const bf16x8*)&lds[row * TRW + c];
            }
        }
        __syncthreads();
    }
}

// ---------------- kernel 3: key conv2 (+k2) || q conv2+conv3 ----------------
__global__ __launch_bounds__(256) void conv2_both(
    const unsigned short* __restrict__ Wk2, const unsigned short* __restrict__ K1t,
    const float* __restrict__ kb2, unsigned short* __restrict__ Kt,
    float* __restrict__ k2s,
    const unsigned short* __restrict__ W2, const unsigned short* __restrict__ W3,
    const float* __restrict__ b2, const float* __restrict__ b3,
    const unsigned short* __restrict__ Q1t, unsigned short* __restrict__ Qt)
{
    constexpr int LDW = 40, TRW = 136, X2W = 104;
    __shared__ unsigned short lds[23552];
    unsigned short* Al = lds;
    unsigned short* Bl = lds + 5120;

    const int tid  = threadIdx.x;
    const int lane = tid & 63;
    const int wid  = tid >> 6;
    const int wm   = wid >> 1;
    const int wn   = wid & 1;
    const int r0 = tid >> 2;
    const int r1 = r0 + 64;
    const int q0 = (tid & 3) * 8;
    const int fr = lane & 15;
    const int ko = (lane >> 4) * 8;

    if (blockIdx.x < 100) {
        // ---- key conv2: 128co x 128n, K=1024, reg-staged, + k2 ----
        const int n0 = blockIdx.x * 128;
        f32x4 acc[4][4] = {};

        bf16x8 ra0 = *(const bf16x8*)&Wk2[(size_t)r0 * 1024 + q0];
        bf16x8 ra1 = *(const bf16x8*)&Wk2[(size_t)r1 * 1024 + q0];
        bf16x8 rb0 = *(const bf16x8*)&K1t[(size_t)(n0 + r0) * 1024 + q0];
        bf16x8 rb1 = *(const bf16x8*)&K1t[(size_t)(n0 + r1) * 1024 + q0];

        for (int kk = 0; kk < 32; kk++) {
            __syncthreads();
            *(bf16x8*)&Al[r0 * LDW + q0] = ra0;
            *(bf16x8*)&Al[r1 * LDW + q0] = ra1;
            *(bf16x8*)&Bl[r0 * LDW + q0] = rb0;
            *(bf16x8*)&Bl[r1 * LDW + q0] = rb1;
            __syncthreads();

            if (kk < 31) {
                int ci0 = (kk + 1) * 32;
                ra0 = *(const bf16x8*)&Wk2[(size_t)r0 * 1024 + ci0 + q0];
                ra1 = *(const bf16x8*)&Wk2[(size_t)r1 * 1024 + ci0 + q0];
                rb0 = *(const bf16x8*)&K1t[(size_t)(n0 + r0) * 1024 + ci0 + q0];
                rb1 = *(const bf16x8*)&K1t[(size_t)(n0 + r1) * 1024 + ci0 + q0];
            }

            bf16x8 af[4], bfr[4];
#pragma unroll
            for (int mi = 0; mi < 4; mi++)
                af[mi] = *(const bf16x8*)&Al[(wm * 64 + mi * 16 + fr) * LDW + ko];
#pragma unroll
            for (int ni = 0; ni < 4; ni++)
                bfr[ni] = *(const bf16x8*)&Bl[(wn * 64 + ni * 16 + fr) * LDW + ko];
#pragma unroll
            for (int mi = 0; mi < 4; mi++)
#pragma unroll
                for (int ni = 0; ni < 4; ni++)
                    acc[mi][ni] = __builtin_amdgcn_mfma_f32_16x16x32_bf16(
                        af[mi], bfr[ni], acc[mi][ni], 0, 0, 0);
        }

#pragma unroll
        for (int p = 0; p < 2; p++) {
            __syncthreads();
            if (wn == p) {
#pragma unroll
                for (int mi = 0; mi < 4; mi++) {
                    int col = wm * 64 + mi * 16 + (lane >> 4) * 4;
#pragma unroll
                    for (int ni = 0; ni < 4; ni++) {
                        int row = ni * 16 + fr;
                        unsigned short pk[4];
#pragma unroll
                        for (int r = 0; r < 4; r++) {
                            int co = col + r;
                            float v = 0.f;
                            if (co < 80) v = acc[mi][ni][r] + kb2[co];
                            pk[r] = f2bf(v);
                        }
                        *(unsigned long long*)&lds[row * TRW + col] = *(unsigned long long*)pk;
                    }
                }
            }
            __syncthreads();
            int rr = tid >> 2;
            int c0 = (tid & 3) * 32;
            int n  = n0 + p * 64 + rr;
            unsigned short* dst = Kt + (size_t)n * 96;
            float s = 0.f;
#pragma unroll
            for (int c = c0; c < c0 + 32; c += 8) {
                if (c < 96) {
                    bf16x8 v = *(const bf16x8*)&lds[rr * TRW + c];
                    *(bf16x8*)&dst[c] = v;
#pragma unroll
                    for (int e = 0; e < 8; e++) {
                        float f = bf2f((unsigned short)v[e]);
                        s = fmaf(f, f, s);
                    }
                }
            }
            s += __shfl_xor(s, 1);
            s += __shfl_xor(s, 2);
            if ((tid & 3) == 0) k2s[n] = s;
        }
    } else {
        // ---- q conv2 + conv3 fused ----
        unsigned short* X2 = lds + 10240;
        const int n0 = (blockIdx.x - 100) * 128;

        f32x4 acc[4][4] = {};

        bf16x8 ra0 = *(const bf16x8*)&W2[(size_t)r0 * 160 + q0];
        bf16x8 ra1 = *(const bf16x8*)&W2[(size_t)r1 * 160 + q0];
        bf16x8 rb0 = *(const bf16x8*)&Q1t[(size_t)(n0 + r0) * 160 + q0];
        bf16x8 rb1 = *(const bf16x8*)&Q1t[(size_t)(n0 + r1) * 160 + q0];

        for (int kk = 0; kk < 5; kk++) {
            __syncthreads();
            *(bf16x8*)&Al[r0 * LDW + q0] = ra0;
            *(bf16x8*)&Al[r1 * LDW + q0] = ra1;
            *(bf16x8*)&Bl[r0 * LDW + q0] = rb0;
            *(bf16x8*)&Bl[r1 * LDW + q0] = rb1;
            __syncthreads();

            if (kk < 4) {
                int ci0 = (kk + 1) * 32;
                ra0 = *(const bf16x8*)&W2[(size_t)r0 * 160 + ci0 + q0];
                ra1 = *(const bf16x8*)&W2[(size_t)r1 * 160 + ci0 + q0];
                rb0 = *(const bf16x8*)&Q1t[(size_t)(n0 + r0) * 160 + ci0 + q0];
                rb1 = *(const bf16x8*)&Q1t[(size_t)(n0 + r1) * 160 + ci0 + q0];
            }

            bf16x8 af[4], bfr[4];
#pragma unroll
            for (int mi = 0; mi < 4; mi++)
                af[mi] = *(const bf16x8*)&Al[(wm * 64 + mi * 16 + fr) * LDW + ko];
#pragma unroll
            for (int ni = 0; ni < 4; ni++)
                bfr[ni] = *(const bf16x8*)&Bl[(wn * 64 + ni * 16 + fr) * LDW + ko];
#pragma unroll
            for (int mi = 0; mi < 4; mi++)
#pragma unroll
                for (int ni = 0; ni < 4; ni++)
                    acc[mi][ni] = __builtin_amdgcn_mfma_f32_16x16x32_bf16(
                        af[mi], bfr[ni], acc[mi][ni], 0, 0, 0);
        }

#pragma unroll
        for (int mi = 0; mi < 4; mi++) {
            int col = wm * 64 + mi * 16 + (lane >> 4) * 4;
            if (col >= 96) continue;
#pragma unroll
            for (int ni = 0; ni < 4; ni++) {
                int row = wn * 64 + ni * 16 + fr;
                unsigned short pk[4];
#pragma unroll
                for (int r = 0; r < 4; r++) {
                    int co = col + r;
                    float v = 0.f;
                    if (co < 80) v = fmaxf(acc[mi][ni][r] + b2[co], 0.f);
                    pk[r] = f2bf(v);
                }
                *(unsigned long long*)&X2[row * X2W + col] = *(unsigned long long*)pk;
            }
        }

#pragma unroll
        for (int mi = 0; mi < 4; mi++)
#pragma unroll
            for (int ni = 0; ni < 4; ni++)
                acc[mi][ni] = (f32x4){0.f, 0.f, 0.f, 0.f};

        ra0 = *(const bf16x8*)&W3[(size_t)r0 * 96 + q0];
        ra1 = *(const bf16x8*)&W3[(size_t)r1 * 96 + q0];

        for (int kk = 0; kk < 3; kk++) {
            __syncthreads();
            *(bf16x8*)&Al[r0 * LDW + q0] = ra0;
            *(bf16x8*)&Al[r1 * LDW + q0] = ra1;
            __syncthreads();

            if (kk < 2) {
                int ci0 = (kk + 1) * 32;
                ra0 = *(const bf16x8*)&W3[(size_t)r0 * 96 + ci0 + q0];
                ra1 = *(const bf16x8*)&W3[(size_t)r1 * 96 + ci0 + q0];
            }

            bf16x8 af[4], bfr[4];
#pragma unroll
            for (int mi = 0; mi < 4; mi++)
                af[mi] = *(const bf16x8*)&Al[(wm * 64 + mi * 16 + fr) * LDW + ko];
#pragma unroll
            for (int ni = 0; ni < 4; ni++)
                bfr[ni] = *(const bf16x8*)&X2[(wn * 64 + ni * 16 + fr) * X2W + kk * 32 + ko];
#pragma unroll
            for (int mi = 0; mi < 4; mi++)
#pragma unroll
                for (int ni = 0; ni < 4; ni++)
                    acc[mi][ni] = __builtin_amdgcn_mfma_f32_16x16x32_bf16(
                        af[mi], bfr[ni], acc[mi][ni], 0, 0, 0);
        }

#pragma unroll
        for (int p = 0; p < 2; p++) {
            __syncthreads();
            if (wn == p) {
#pragma unroll
                for (int mi = 0; mi < 4; mi++) {
                    int col = wm * 64 + mi * 16 + (lane >> 4) * 4;
#pragma unroll
                    for (int ni = 0; ni < 4; ni++) {
                        int row = ni * 16 + fr;
                        unsigned short pk[4];
#pragma unroll
                        for (int r = 0; r < 4; r++) {
                            int co = col + r;
                            float v = 0.f;
                            if (co < 80) v = acc[mi][ni][r] + b3[co];
                            pk[r] = f2bf(v);
                        }
                        *(unsigned long long*)&lds[row * TRW + col] = *(unsigned long long*)pk;
                    }
                }
            }
            __syncthreads();
            int rr = tid >> 2;
            int c0 = (tid & 3) * 32;
            int n  = n0 + p * 64 + rr;
            unsigned short* dst = Qt + (size_t)n * 96;
#pragma unroll
            for (int c = c0; c < c0 + 32; c += 8)
                if (c < 96)
                    *(bf16x8*)&dst[c] = *(const bf16x8*)&lds[rr * TRW + c];
        }
    }
}

// ---------------- kernel 4: fused MFMA-QK + softmax/logprob ----------------
#define NS 7
#define SCW 404
__global__ __launch_bounds__(512) void attn_v2(
    const unsigned short* __restrict__ Kt,   // [32*400][96] bf16
    const unsigned short* __restrict__ Qt,   // [32*1600][96] bf16
    const float* __restrict__ k2s,           // [32*400]
    const float* __restrict__ prior, const int* __restrict__ mask,
    float* __restrict__ out_attn, float* __restrict__ out_lp)
{
    const int T1 = 1600, T2 = 400;
    __shared__ float Sc[32 * SCW];

    const int tid  = threadIdx.x;
    const int lane = tid & 63;
    const int wid  = tid >> 6;
    const int b    = blockIdx.y;
    const int t0   = blockIdx.x * 32;
    const int fr   = lane & 15;
    const int ko   = (lane >> 4) * 8;

    bf16x8 qf[2][3];
#pragma unroll
    for (int ts = 0; ts < 2; ts++)
#pragma unroll
        for (int kk = 0; kk < 3; kk++)
            qf[ts][kk] = *(const bf16x8*)&Qt[((size_t)b * T1 + t0 + ts * 16 + fr) * 96 + kk * 32 + ko];

    for (int st = wid; st < 25; st += 8) {
        f32x4 acc0 = {}, acc1 = {};
#pragma unroll
        for (int kk = 0; kk < 3; kk++) {
            bf16x8 kf = *(const bf16x8*)&Kt[((size_t)b * T2 + st * 16 + fr) * 96 + kk * 32 + ko];
            acc0 = __builtin_amdgcn_mfma_f32_16x16x32_bf16(kf, qf[0][kk], acc0, 0, 0, 0);
            acc1 = __builtin_amdgcn_mfma_f32_16x16x32_bf16(kf, qf[1][kk], acc1, 0, 0, 0);
        }
        int sbase = st * 16 + (lane >> 4) * 4;
        float4 kv = *(const float4*)&k2s[b * T2 + sbase];
        float4 w0, w1;
        w0.x = fmaf(1e-3f, acc0[0], -5e-4f * kv.x);
        w0.y = fmaf(1e-3f, acc0[1], -5e-4f * kv.y);
        w0.z = fmaf(1e-3f, acc0[2], -5e-4f * kv.z);
        w0.w = fmaf(1e-3f, acc0[3], -5e-4f * kv.w);
        w1.x = fmaf(1e-3f, acc1[0], -5e-4f * kv.x);
        w1.y = fmaf(1e-3f, acc1[1], -5e-4f * kv.y);
        w1.z = fmaf(1e-3f, acc1[2], -5e-4f * kv.z);
        w1.w = fmaf(1e-3f, acc1[3], -5e-4f * kv.w);
        *(float4*)&Sc[fr * SCW + sbase]        = w0;
        *(float4*)&Sc[(16 + fr) * SCW + sbase] = w1;
    }

    int mk[NS];
#pragma unroll
    for (int j = 0; j < NS; j++) {
        int s = lane + 64 * j;
        mk[j] = (s < T2) ? mask[b * T2 + s] : 1;
    }

    __syncthreads();

    for (int r = 0; r < 4; r++) {
        int tloc = wid * 4 + r;
        int t = t0 + tloc;

        float scr[NS];
        float m = -INFINITY;
#pragma unroll
        for (int j = 0; j < NS; j++) {
            int s = lane + 64 * j;
            if (s < T2) {
                scr[j] = Sc[tloc * SCW + s];
                m = fmaxf(m, scr[j]);
            } else {
                scr[j] = -INFINITY;
            }
        }
#pragma unroll
        for (int o = 32; o >= 1; o >>= 1) m = fmaxf(m, __shfl_xor(m, o));
        float sum = 0.f;
#pragma unroll
        for (int j = 0; j < NS; j++) {
            int s = lane + 64 * j;
            if (s < T2) sum += __expf(scr[j] - m);
        }
#pragma unroll
        for (int o = 32; o >= 1; o >>= 1) sum += __shfl_xor(sum, o);
        float lse = m + __logf(sum);

        const float* pr = prior + ((size_t)b * T1 + t) * T2;
        float* lpout = out_lp + ((size_t)b * T1 + t) * T2;
        float* atout = out_attn + ((size_t)b * T1 + t) * T2;

        float val[NS];
        float m2 = -INFINITY;
#pragma unroll
        for (int j = 0; j < NS; j++) {
            int s = lane + 64 * j;
            if (s < T2) {
                float lp = scr[j] - lse + __logf(pr[s] + 1e-8f);
                lpout[s] = lp;
                val[j] = mk[j] ? -INFINITY : lp;
                m2 = fmaxf(m2, val[j]);
            } else {
                val[j] = -INFINITY;
            }
        }
#pragma unroll
        for (int o = 32; o >= 1; o >>= 1) m2 = fmaxf(m2, __shfl_xor(m2, o));
        float ex[NS];
        float sum2 = 0.f;
#pragma unroll
        for (int j = 0; j < NS; j++) { ex[j] = __expf(val[j] - m2); sum2 += ex[j]; }
#pragma unroll
        for (int o = 32; o >= 1; o >>= 1) sum2 += __shfl_xor(sum2, o);
        float inv = 1.f / sum2;
#pragma unroll
        for (int j = 0; j < NS; j++) {
            int s = lane + 64 * j;
            if (s < T2) atout[s] = ex[j] * inv;
        }
    }
}

// ---------------------------------------------------------------------------
extern "C" void kernel_launch(void* const* d_in, const int* in_sizes, int n_in,
                              void* d_out, int out_size, void* d_ws, size_t ws_size,
                              hipStream_t stream)
{
    (void)in_sizes; (void)n_in; (void)out_size; (void)ws_size;

    const float* queries = (const float*)d_in[0];
    const float* keys    = (const float*)d_in[1];
    const float* prior   = (const float*)d_in[2];
    const int*   mask    = (const int*)d_in[3];
    const float* kw1     = (const float*)d_in[4];
    const float* kb1     = (const float*)d_in[5];
    const float* kw2     = (const float*)d_in[6];
    const float* kb2     = (const float*)d_in[7];
    const float* qw1     = (const float*)d_in[8];
    const float* qb1     = (const float*)d_in[9];
    const float* qw2     = (const float*)d_in[10];
    const float* qb2     = (const float*)d_in[11];
    const float* qw3     = (const float*)d_in[12];
    const float* qb3     = (const float*)d_in[13];

    unsigned short* U = (unsigned short*)d_ws;
    unsigned short* K1t = U;                        // [12800][1024]
    unsigned short* Q1t = U;                        // [51200][160] (reuse)
    unsigned short* Xk  = U + 13107200;             // [13058][512]
    unsigned short* Qt  = U + 13107200;             // [51200][96] (reuse after key path)
    unsigned short* Xq  = U + 19792896;             // [51458][96]
    unsigned short* Kt  = U + 24732864;             // [12800][96]
    unsigned short* Wk1 = U + 25961664;             // 3*1024*512
    unsigned short* Wk2 = U + 27534528;             // 128*1024
    unsigned short* Wq1 = U + 27665600;             // 3*256*96
    unsigned short* Wq2 = U + 27739328;             // 128*160
    unsigned short* Wq3 = U + 27759808;             // 128*96
    float*          k2s = (float*)(U + 27772096);   // 12800 f32

    float* out_attn = (float*)d_out;
    float* out_lp   = out_attn + (size_t)32 * 1600 * 400;

    // 1) all prep: both input transposes + all weight converts + tail zeroes
    prep_all<<<NKB + NQB + NFB, dim3(256), 0, stream>>>(
        keys, queries, kw1, kw2, qw1, qw2, qw3,
        Xk, Xq, Wk1, Wk2, Wq1, Wq2, Wq3);

    // 2) both 3-tap convs in one launch (key 204 + q 201, balanced per XCD)
    conv1_both<<<405, dim3(512), 0, stream>>>(
        Wk1, Xk, kb1, K1t, Wq1, Xq, qb1, Q1t);

    // 3) key conv2 (+k2) || q conv2+conv3 fused
    conv2_both<<<500, dim3(256), 0, stream>>>(
        Wk2, K1t, kb2, Kt, k2s, Wq2, Wq3, qb2, qb3, Q1t, Qt);

    // 4) fused attention + softmaxes
    attn_v2<<<dim3(50, 32), dim3(512), 0, stream>>>(
        Kt, Qt, k2s, prior, mask, out_attn, out_lp);
}

// Round 14
// 222.201 us; speedup vs baseline: 1.2306x; 1.2306x over previous
//
#include <hip/hip_runtime.h>
#include <math.h>

// ---------------------------------------------------------------------------
// ConvAttention (B=32, T1=1600, T2=400, n_mel=80, n_text=512, n_att=80)
// Round 14: revert conv1_both to r12 (128x256, vmcnt(3), balanced per-range
//   XCD swizzle, T2 chunk swizzle — 96us proven; r13's 256² tile regressed
//   from 2-blocks/CU occupancy + grid tail). NEW: attn_v2 memory ops
//   vectorized to float4 via s = lane*4 + 256*j lane mapping (G13).
// ---------------------------------------------------------------------------

typedef __attribute__((ext_vector_type(8))) short bf16x8;
typedef __attribute__((ext_vector_type(4))) float f32x4;

static __device__ __forceinline__ unsigned short f2bf(float f) {
    union { float f; unsigned u; } v; v.f = f;
    unsigned r = v.u + 0x7FFF + ((v.u >> 16) & 1);
    return (unsigned short)(r >> 16);
}
static __device__ __forceinline__ float bf2f(unsigned short h) {
    union { unsigned u; float f; } v; v.u = ((unsigned)h) << 16;
    return v.f;
}

#define GLOAD16(g, s) __builtin_amdgcn_global_load_lds( \
    (const __attribute__((address_space(1))) void*)(g), \
    (__attribute__((address_space(3))) void*)(s), 16, 0, 0)

// ---------------- kernel 1: all prep ----------------
static __device__ __forceinline__ void fill_w(
    const float* __restrict__ w, unsigned short* __restrict__ dst, int rem,
    int Cout, int Cin, int KTAP, int CoutAlloc, int CinPad)
{
    int d  = rem / (CoutAlloc * CinPad);
    int r2 = rem - d * (CoutAlloc * CinPad);
    int co = r2 / CinPad, ci = r2 - co * CinPad;
    float v = (co < Cout && ci < Cin) ? w[((size_t)co * Cin + ci) * KTAP + d] : 0.f;
    dst[rem] = f2bf(v);
}

#define S0 1572864       // Wk1 3*1024*512
#define S1 (S0+131072)   // Wk2 128*1024
#define S2 (S1+73728)    // Wq1 3*256*96
#define S3 (S2+20480)    // Wq2 128*160
#define S4 (S3+12288)    // Wq3 128*96
#define S5 (S4+66560)    // Xk tail 130*512
#define S6 (S5+12480)    // Xq tail 130*96
#define NKB 6656         // 13*16*32 key transpose blocks
#define NQB 4896         // 51*3*32  query transpose blocks
#define NFB ((S6+255)/256)

static __device__ __forceinline__ void transpose_body(
    const float* __restrict__ in, unsigned short* __restrict__ Xt,
    int C, int CinPad, int T, int Trow,
    int bx, int by, int bz, float s[32][33])
{
    int ci0 = by * 32, tr0 = bx * 32;
    int tx = threadIdx.x & 31, ty = threadIdx.x >> 5;
#pragma unroll
    for (int i = 0; i < 4; i++) {
        int c = ci0 + ty + 8 * i;
        int t_in = tr0 + tx - 1;
        float v = (c < C && t_in >= 0 && t_in < T)
                    ? in[((size_t)bz * C + c) * T + t_in] : 0.f;
        s[ty + 8 * i][tx] = v;
    }
    __syncthreads();
#pragma unroll
    for (int i = 0; i < 4; i++) {
        int tr = tr0 + ty + 8 * i;
        if (tr < Trow)
            Xt[((size_t)bz * Trow + tr) * CinPad + ci0 + tx] = f2bf(s[tx][ty + 8 * i]);
    }
}

__global__ __launch_bounds__(256) void prep_all(
    const float* __restrict__ keys, const float* __restrict__ queries,
    const float* __restrict__ kw1, const float* __restrict__ kw2,
    const float* __restrict__ qw1, const float* __restrict__ qw2,
    const float* __restrict__ qw3,
    unsigned short* __restrict__ Xk, unsigned short* __restrict__ Xq,
    unsigned short* __restrict__ Wk1, unsigned short* __restrict__ Wk2,
    unsigned short* __restrict__ Wq1, unsigned short* __restrict__ Wq2,
    unsigned short* __restrict__ Wq3)
{
    __shared__ float s[32][33];
    int bxg = blockIdx.x;
    if (bxg < NKB) {
        int x = bxg % 13, y = (bxg / 13) & 15, z = bxg / (13 * 16);
        transpose_body(keys, Xk, 512, 512, 400, 404, x, y, z, s);
    } else if (bxg < NKB + NQB) {
        int b2 = bxg - NKB;
        int x = b2 % 51, y = (b2 / 51) % 3, z = b2 / 153;
        transpose_body(queries, Xq, 80, 96, 1600, 1604, x, y, z, s);
    } else {
        int idx = (bxg - NKB - NQB) * 256 + threadIdx.x;
        if (idx < S0)      fill_w(kw1, Wk1, idx,       1024, 512, 3, 1024, 512);
        else if (idx < S1) fill_w(kw2, Wk2, idx - S0,  80, 1024, 1, 128, 1024);
        else if (idx < S2) fill_w(qw1, Wq1, idx - S1,  160, 80, 3, 256, 96);
        else if (idx < S3) fill_w(qw2, Wq2, idx - S2,  80, 160, 1, 128, 160);
        else if (idx < S4) fill_w(qw3, Wq3, idx - S3,  80, 80, 1, 128, 96);
        else if (idx < S5) Xk[(size_t)12928 * 512 + (idx - S4)] = 0;
        else if (idx < S6) Xq[(size_t)51328 * 96  + (idx - S5)] = 0;
    }
}

// ---------------- kernel 2: both 3-tap convs (128x256, counted vmcnt) -------
__global__ __launch_bounds__(512) void conv1_both(
    const unsigned short* __restrict__ Wk1, const unsigned short* __restrict__ Xk,
    const float* __restrict__ kb1, unsigned short* __restrict__ K1t,
    const unsigned short* __restrict__ Wq1, const unsigned short* __restrict__ Xq,
    const float* __restrict__ qb1, unsigned short* __restrict__ Q1t)
{
    constexpr int TRW = 136;
    __shared__ unsigned short lds[24576]; // 2 bufs x (A[128][32] + B[256][32])

    const int tid  = threadIdx.x;
    const int lane = tid & 63;
    const int wid  = tid >> 6;
    const int wm   = wid >> 2;
    const int wn   = wid & 3;

    const int bid = blockIdx.x;
    const unsigned short* Wbf; const unsigned short* Xt;
    const float* bias; unsigned short* out;
    int CinPad, CoutAlloc, Cout, Trow, Tout, OutStride, nCo, Nvalid, wgid;
    if (bid < 408) {
        int xcd = bid & 7, ix = bid >> 3;
        wgid = xcd * 51 + ix;
        Wbf = Wk1; Xt = Xk; bias = kb1; out = K1t;
        CinPad = 512; CoutAlloc = 1024; Cout = 1024; Trow = 404; Tout = 400;
        OutStride = 1024; nCo = 8; Nvalid = 12928;
    } else {
        int b2 = bid - 408;
        int xcd = b2 & 7, ix = b2 >> 3;
        wgid = (xcd < 2 ? xcd * 51 : 2 * 51 + (xcd - 2) * 50) + ix;
        Wbf = Wq1; Xt = Xq; bias = qb1; out = Q1t;
        CinPad = 96; CoutAlloc = 256; Cout = 160; Trow = 1604; Tout = 1600;
        OutStride = 160; nCo = 2; Nvalid = 51328;
    }
    const int co0 = (wgid % nCo) * 128;
    const int n0  = (wgid / nCo) * 256;

    const int lr = lane >> 2;
    const int fr = lane & 15;
    // T2 chunk swizzle (r12): slot (row,c) holds global chunk c ^ ((row&15)>>1 & 3)
    const int lc = (((lane & 3) ^ ((lr >> 1) & 3)) * 8);
    const int ko = (((lane >> 4) ^ ((fr >> 1) & 3)) * 8);

    const int nKc   = CinPad >> 5;
    const int nIter = 3 * nKc;

    f32x4 a4[4][4] = {};

    int scc = 0, sd = 0;
#define STAGE(B)                                                                  \
    {                                                                             \
        const unsigned short* asrc =                                              \
            Wbf + ((size_t)sd * CoutAlloc + co0 + wid * 16 + lr) * CinPad + scc * 32 + lc; \
        const unsigned short* bsrc =                                              \
            Xt + ((size_t)(n0 + sd) + wid * 32 + lr) * CinPad + scc * 32 + lc;    \
        unsigned short* Ab = lds + (B) * 12288;                                   \
        GLOAD16(asrc, &Ab[wid * 512]);                                            \
        GLOAD16(bsrc, &Ab[4096 + wid * 1024]);                                    \
        GLOAD16(bsrc + (size_t)16 * CinPad, &Ab[4096 + wid * 1024 + 512]);        \
        scc++; if (scc == nKc) { scc = 0; sd++; }                                 \
    }

#define COMPUTE(B)                                                                \
    {                                                                             \
        const unsigned short* Ab = lds + (B) * 12288;                             \
        const unsigned short* Bb = Ab + 4096;                                     \
        bf16x8 af[4], bfr[4];                                                     \
        _Pragma("unroll")                                                         \
        for (int mi = 0; mi < 4; mi++)                                            \
            af[mi] = *(const bf16x8*)&Ab[(wm * 64 + mi * 16 + fr) * 32 + ko];     \
        _Pragma("unroll")                                                         \
        for (int ni = 0; ni < 4; ni++)                                            \
            bfr[ni] = *(const bf16x8*)&Bb[(wn * 64 + ni * 16 + fr) * 32 + ko];    \
        _Pragma("unroll")                                                         \
        for (int mi = 0; mi < 4; mi++)                                            \
            _Pragma("unroll")                                                     \
            for (int ni = 0; ni < 4; ni++)                                        \
                a4[mi][ni] = __builtin_amdgcn_mfma_f32_16x16x32_bf16(             \
                    af[mi], bfr[ni], a4[mi][ni], 0, 0, 0);                        \
    }

    STAGE(0);
    STAGE(1);

    for (int t = 0; t < nIter; t++) {
        if (t < nIter - 1)
            asm volatile("s_waitcnt vmcnt(3)" ::: "memory");
        else
            asm volatile("s_waitcnt vmcnt(0)" ::: "memory");
        __builtin_amdgcn_s_barrier();
        COMPUTE(t & 1);
        __builtin_amdgcn_sched_barrier(0);
        __builtin_amdgcn_s_barrier();
        if (t + 2 < nIter) STAGE(t & 1);
    }
#undef STAGE
#undef COMPUTE

    __syncthreads();

    int cw = OutStride - co0; if (cw > 128) cw = 128;
#pragma unroll
    for (int p = 0; p < 4; p++) {
        if (wn == p) {
#pragma unroll
            for (int mi = 0; mi < 4; mi++) {
                int col = wm * 64 + mi * 16 + (lane >> 4) * 4;
#pragma unroll
                for (int ni = 0; ni < 4; ni++) {
                    int row = ni * 16 + fr;
                    unsigned short pk[4];
#pragma unroll
                    for (int r = 0; r < 4; r++) {
                        int co = co0 + col + r;
                        float v = 0.f;
                        if (co < Cout) v = fmaxf(a4[mi][ni][r] + bias[co], 0.f);
                        pk[r] = f2bf(v);
                    }
                    *(unsigned long long*)&lds[row * TRW + col] = *(unsigned long long*)pk;
                }
            }
        }
        __syncthreads();
        int row = tid >> 3;
        int c0  = (tid & 7) * 16;
        int n   = n0 + p * 64 + row;
        if (n < Nvalid && c0 < cw) {
            int b = n / Trow;
            int t = n - b * Trow;
            if (t < Tout) {
                unsigned short* dst = out + ((size_t)b * Tout + t) * OutStride + co0 + c0;
                *(bf16x8*)&dst[0] = *(const bf16x8*)&lds[row * TRW + c0];
                *(bf16x8*)&dst[8] = *(const bf16x8*)&lds[row * TRW + c0 + 8];
            }
        }
        __syncthreads();
    }
}

// ---------------- kernel 3: key conv2 (+k2) || q conv2+conv3 ----------------
__global__ __launch_bounds__(256) void conv2_both(
    const unsigned short* __restrict__ Wk2, const unsigned short* __restrict__ K1t,
    const float* __restrict__ kb2, unsigned short* __restrict__ Kt,
    float* __restrict__ k2s,
    const unsigned short* __restrict__ W2, const unsigned short* __restrict__ W3,
    const float* __restrict__ b2, const float* __restrict__ b3,
    const unsigned short* __restrict__ Q1t, unsigned short* __restrict__ Qt)
{
    constexpr int LDW = 40, TRW = 136, X2W = 104;
    __shared__ unsigned short lds[23552];
    unsigned short* Al = lds;
    unsigned short* Bl = lds + 5120;

    const int tid  = threadIdx.x;
    const int lane = tid & 63;
    const int wid  = tid >> 6;
    const int wm   = wid >> 1;
    const int wn   = wid & 1;
    const int r0 = tid >> 2;
    const int r1 = r0 + 64;
    const int q0 = (tid & 3) * 8;
    const int fr = lane & 15;
    const int ko = (lane >> 4) * 8;

    if (blockIdx.x < 100) {
        const int n0 = blockIdx.x * 128;
        f32x4 acc[4][4] = {};

        bf16x8 ra0 = *(const bf16x8*)&Wk2[(size_t)r0 * 1024 + q0];
        bf16x8 ra1 = *(const bf16x8*)&Wk2[(size_t)r1 * 1024 + q0];
        bf16x8 rb0 = *(const bf16x8*)&K1t[(size_t)(n0 + r0) * 1024 + q0];
        bf16x8 rb1 = *(const bf16x8*)&K1t[(size_t)(n0 + r1) * 1024 + q0];

        for (int kk = 0; kk < 32; kk++) {
            __syncthreads();
            *(bf16x8*)&Al[r0 * LDW + q0] = ra0;
            *(bf16x8*)&Al[r1 * LDW + q0] = ra1;
            *(bf16x8*)&Bl[r0 * LDW + q0] = rb0;
            *(bf16x8*)&Bl[r1 * LDW + q0] = rb1;
            __syncthreads();

            if (kk < 31) {
                int ci0 = (kk + 1) * 32;
                ra0 = *(const bf16x8*)&Wk2[(size_t)r0 * 1024 + ci0 + q0];
                ra1 = *(const bf16x8*)&Wk2[(size_t)r1 * 1024 + ci0 + q0];
                rb0 = *(const bf16x8*)&K1t[(size_t)(n0 + r0) * 1024 + ci0 + q0];
                rb1 = *(const bf16x8*)&K1t[(size_t)(n0 + r1) * 1024 + ci0 + q0];
            }

            bf16x8 af[4], bfr[4];
#pragma unroll
            for (int mi = 0; mi < 4; mi++)
                af[mi] = *(const bf16x8*)&Al[(wm * 64 + mi * 16 + fr) * LDW + ko];
#pragma unroll
            for (int ni = 0; ni < 4; ni++)
                bfr[ni] = *(const bf16x8*)&Bl[(wn * 64 + ni * 16 + fr) * LDW + ko];
#pragma unroll
            for (int mi = 0; mi < 4; mi++)
#pragma unroll
                for (int ni = 0; ni < 4; ni++)
                    acc[mi][ni] = __builtin_amdgcn_mfma_f32_16x16x32_bf16(
                        af[mi], bfr[ni], acc[mi][ni], 0, 0, 0);
        }

#pragma unroll
        for (int p = 0; p < 2; p++) {
            __syncthreads();
            if (wn == p) {
#pragma unroll
                for (int mi = 0; mi < 4; mi++) {
                    int col = wm * 64 + mi * 16 + (lane >> 4) * 4;
#pragma unroll
                    for (int ni = 0; ni < 4; ni++) {
                        int row = ni * 16 + fr;
                        unsigned short pk[4];
#pragma unroll
                        for (int r = 0; r < 4; r++) {
                            int co = col + r;
                            float v = 0.f;
                            if (co < 80) v = acc[mi][ni][r] + kb2[co];
                            pk[r] = f2bf(v);
                        }
                        *(unsigned long long*)&lds[row * TRW + col] = *(unsigned long long*)pk;
                    }
                }
            }
            __syncthreads();
            int rr = tid >> 2;
            int c0 = (tid & 3) * 32;
            int n  = n0 + p * 64 + rr;
            unsigned short* dst = Kt + (size_t)n * 96;
            float s = 0.f;
#pragma unroll
            for (int c = c0; c < c0 + 32; c += 8) {
                if (c < 96) {
                    bf16x8 v = *(const bf16x8*)&lds[rr * TRW + c];
                    *(bf16x8*)&dst[c] = v;
#pragma unroll
                    for (int e = 0; e < 8; e++) {
                        float f = bf2f((unsigned short)v[e]);
                        s = fmaf(f, f, s);
                    }
                }
            }
            s += __shfl_xor(s, 1);
            s += __shfl_xor(s, 2);
            if ((tid & 3) == 0) k2s[n] = s;
        }
    } else {
        unsigned short* X2 = lds + 10240;
        const int n0 = (blockIdx.x - 100) * 128;

        f32x4 acc[4][4] = {};

        bf16x8 ra0 = *(const bf16x8*)&W2[(size_t)r0 * 160 + q0];
        bf16x8 ra1 = *(const bf16x8*)&W2[(size_t)r1 * 160 + q0];
        bf16x8 rb0 = *(const bf16x8*)&Q1t[(size_t)(n0 + r0) * 160 + q0];
        bf16x8 rb1 = *(const bf16x8*)&Q1t[(size_t)(n0 + r1) * 160 + q0];

        for (int kk = 0; kk < 5; kk++) {
            __syncthreads();
            *(bf16x8*)&Al[r0 * LDW + q0] = ra0;
            *(bf16x8*)&Al[r1 * LDW + q0] = ra1;
            *(bf16x8*)&Bl[r0 * LDW + q0] = rb0;
            *(bf16x8*)&Bl[r1 * LDW + q0] = rb1;
            __syncthreads();

            if (kk < 4) {
                int ci0 = (kk + 1) * 32;
                ra0 = *(const bf16x8*)&W2[(size_t)r0 * 160 + ci0 + q0];
                ra1 = *(const bf16x8*)&W2[(size_t)r1 * 160 + ci0 + q0];
                rb0 = *(const bf16x8*)&Q1t[(size_t)(n0 + r0) * 160 + ci0 + q0];
                rb1 = *(const bf16x8*)&Q1t[(size_t)(n0 + r1) * 160 + ci0 + q0];
            }

            bf16x8 af[4], bfr[4];
#pragma unroll
            for (int mi = 0; mi < 4; mi++)
                af[mi] = *(const bf16x8*)&Al[(wm * 64 + mi * 16 + fr) * LDW + ko];
#pragma unroll
            for (int ni = 0; ni < 4; ni++)
                bfr[ni] = *(const bf16x8*)&Bl[(wn * 64 + ni * 16 + fr) * LDW + ko];
#pragma unroll
            for (int mi = 0; mi < 4; mi++)
#pragma unroll
                for (int ni = 0; ni < 4; ni++)
                    acc[mi][ni] = __builtin_amdgcn_mfma_f32_16x16x32_bf16(
                        af[mi], bfr[ni], acc[mi][ni], 0, 0, 0);
        }

#pragma unroll
        for (int mi = 0; mi < 4; mi++) {
            int col = wm * 64 + mi * 16 + (lane >> 4) * 4;
            if (col >= 96) continue;
#pragma unroll
            for (int ni = 0; ni < 4; ni++) {
                int row = wn * 64 + ni * 16 + fr;
                unsigned short pk[4];
#pragma unroll
                for (int r = 0; r < 4; r++) {
                    int co = col + r;
                    float v = 0.f;
                    if (co < 80) v = fmaxf(acc[mi][ni][r] + b2[co], 0.f);
                    pk[r] = f2bf(v);
                }
                *(unsigned long long*)&X2[row * X2W + col] = *(unsigned long long*)pk;
            }
        }

#pragma unroll
        for (int mi = 0; mi < 4; mi++)
#pragma unroll
            for (int ni = 0; ni < 4; ni++)
                acc[mi][ni] = (f32x4){0.f, 0.f, 0.f, 0.f};

        ra0 = *(const bf16x8*)&W3[(size_t)r0 * 96 + q0];
        ra1 = *(const bf16x8*)&W3[(size_t)r1 * 96 + q0];

        for (int kk = 0; kk < 3; kk++) {
            __syncthreads();
            *(bf16x8*)&Al[r0 * LDW + q0] = ra0;
            *(bf16x8*)&Al[r1 * LDW + q0] = ra1;
            __syncthreads();

            if (kk < 2) {
                int ci0 = (kk + 1) * 32;
                ra0 = *(const bf16x8*)&W3[(size_t)r0 * 96 + ci0 + q0];
                ra1 = *(const bf16x8*)&W3[(size_t)r1 * 96 + ci0 + q0];
            }

            bf16x8 af[4], bfr[4];
#pragma unroll
            for (int mi = 0; mi < 4; mi++)
                af[mi] = *(const bf16x8*)&Al[(wm * 64 + mi * 16 + fr) * LDW + ko];
#pragma unroll
            for (int ni = 0; ni < 4; ni++)
                bfr[ni] = *(const bf16x8*)&X2[(wn * 64 + ni * 16 + fr) * X2W + kk * 32 + ko];
#pragma unroll
            for (int mi = 0; mi < 4; mi++)
#pragma unroll
                for (int ni = 0; ni < 4; ni++)
                    acc[mi][ni] = __builtin_amdgcn_mfma_f32_16x16x32_bf16(
                        af[mi], bfr[ni], acc[mi][ni], 0, 0, 0);
        }

#pragma unroll
        for (int p = 0; p < 2; p++) {
            __syncthreads();
            if (wn == p) {
#pragma unroll
                for (int mi = 0; mi < 4; mi++) {
                    int col = wm * 64 + mi * 16 + (lane >> 4) * 4;
#pragma unroll
                    for (int ni = 0; ni < 4; ni++) {
                        int row = ni * 16 + fr;
                        unsigned short pk[4];
#pragma unroll
                        for (int r = 0; r < 4; r++) {
                            int co = col + r;
                            float v = 0.f;
                            if (co < 80) v = acc[mi][ni][r] + b3[co];
                            pk[r] = f2bf(v);
                        }
                        *(unsigned long long*)&lds[row * TRW + col] = *(unsigned long long*)pk;
                    }
                }
            }
            __syncthreads();
            int rr = tid >> 2;
            int c0 = (tid & 3) * 32;
            int n  = n0 + p * 64 + rr;
            unsigned short* dst = Qt + (size_t)n * 96;
#pragma unroll
            for (int c = c0; c < c0 + 32; c += 8)
                if (c < 96)
                    *(bf16x8*)&dst[c] = *(const bf16x8*)&lds[rr * TRW + c];
        }
    }
}

// ---------------- kernel 4: fused MFMA-QK + softmax/logprob (float4 I/O) ----
#define SCW 404
__global__ __launch_bounds__(512) void attn_v2(
    const unsigned short* __restrict__ Kt,   // [32*400][96] bf16
    const unsigned short* __restrict__ Qt,   // [32*1600][96] bf16
    const float* __restrict__ k2s,           // [32*400]
    const float* __restrict__ prior, const int* __restrict__ mask,
    float* __restrict__ out_attn, float* __restrict__ out_lp)
{
    const int T1 = 1600, T2 = 400;
    __shared__ float Sc[32 * SCW];

    const int tid  = threadIdx.x;
    const int lane = tid & 63;
    const int wid  = tid >> 6;
    const int b    = blockIdx.y;
    const int t0   = blockIdx.x * 32;
    const int fr   = lane & 15;
    const int ko   = (lane >> 4) * 8;

    bf16x8 qf[2][3];
#pragma unroll
    for (int ts = 0; ts < 2; ts++)
#pragma unroll
        for (int kk = 0; kk < 3; kk++)
            qf[ts][kk] = *(const bf16x8*)&Qt[((size_t)b * T1 + t0 + ts * 16 + fr) * 96 + kk * 32 + ko];

    for (int st = wid; st < 25; st += 8) {
        f32x4 acc0 = {}, acc1 = {};
#pragma unroll
        for (int kk = 0; kk < 3; kk++) {
            bf16x8 kf = *(const bf16x8*)&Kt[((size_t)b * T2 + st * 16 + fr) * 96 + kk * 32 + ko];
            acc0 = __builtin_amdgcn_mfma_f32_16x16x32_bf16(kf, qf[0][kk], acc0, 0, 0, 0);
            acc1 = __builtin_amdgcn_mfma_f32_16x16x32_bf16(kf, qf[1][kk], acc1, 0, 0, 0);
        }
        int sbase = st * 16 + (lane >> 4) * 4;
        float4 kv = *(const float4*)&k2s[b * T2 + sbase];
        float4 w0, w1;
        w0.x = fmaf(1e-3f, acc0[0], -5e-4f * kv.x);
        w0.y = fmaf(1e-3f, acc0[1], -5e-4f * kv.y);
        w0.z = fmaf(1e-3f, acc0[2], -5e-4f * kv.z);
        w0.w = fmaf(1e-3f, acc0[3], -5e-4f * kv.w);
        w1.x = fmaf(1e-3f, acc1[0], -5e-4f * kv.x);
        w1.y = fmaf(1e-3f, acc1[1], -5e-4f * kv.y);
        w1.z = fmaf(1e-3f, acc1[2], -5e-4f * kv.z);
        w1.w = fmaf(1e-3f, acc1[3], -5e-4f * kv.w);
        *(float4*)&Sc[fr * SCW + sbase]        = w0;
        *(float4*)&Sc[(16 + fr) * SCW + sbase] = w1;
    }

    // lane -> s mapping: s = lane*4 + 256*j ; j=0 lanes 0..63, j=1 lanes 0..35
    const int s0i = lane * 4;
    const int s1i = 256 + lane * 4;
    const bool has1 = (lane < 36);

    int4 mk0 = *(const int4*)&mask[b * T2 + s0i];
    int4 mk1 = has1 ? *(const int4*)&mask[b * T2 + s1i] : make_int4(1, 1, 1, 1);

    __syncthreads();

    for (int r = 0; r < 4; r++) {
        int tloc = wid * 4 + r;
        int t = t0 + tloc;

        float4 v0 = *(const float4*)&Sc[tloc * SCW + s0i];
        float4 v1;
        if (has1) v1 = *(const float4*)&Sc[tloc * SCW + s1i];
        else      v1 = make_float4(-INFINITY, -INFINITY, -INFINITY, -INFINITY);

        float m = fmaxf(fmaxf(fmaxf(v0.x, v0.y), fmaxf(v0.z, v0.w)),
                        fmaxf(fmaxf(v1.x, v1.y), fmaxf(v1.z, v1.w)));
#pragma unroll
        for (int o = 32; o >= 1; o >>= 1) m = fmaxf(m, __shfl_xor(m, o));

        float sum = __expf(v0.x - m) + __expf(v0.y - m) + __expf(v0.z - m) + __expf(v0.w - m)
                  + __expf(v1.x - m) + __expf(v1.y - m) + __expf(v1.z - m) + __expf(v1.w - m);
#pragma unroll
        for (int o = 32; o >= 1; o >>= 1) sum += __shfl_xor(sum, o);
        float lse = m + __logf(sum);

        const float* pr = prior + ((size_t)b * T1 + t) * T2;
        float* lpout = out_lp + ((size_t)b * T1 + t) * T2;
        float* atout = out_attn + ((size_t)b * T1 + t) * T2;

        float4 p0 = *(const float4*)&pr[s0i];
        float4 p1 = has1 ? *(const float4*)&pr[s1i] : make_float4(0, 0, 0, 0);

        float4 lp0, lp1;
        lp0.x = v0.x - lse + __logf(p0.x + 1e-8f);
        lp0.y = v0.y - lse + __logf(p0.y + 1e-8f);
        lp0.z = v0.z - lse + __logf(p0.z + 1e-8f);
        lp0.w = v0.w - lse + __logf(p0.w + 1e-8f);
        lp1.x = v1.x - lse + __logf(p1.x + 1e-8f);
        lp1.y = v1.y - lse + __logf(p1.y + 1e-8f);
        lp1.z = v1.z - lse + __logf(p1.z + 1e-8f);
        lp1.w = v1.w - lse + __logf(p1.w + 1e-8f);

        *(float4*)&lpout[s0i] = lp0;
        if (has1) *(float4*)&lpout[s1i] = lp1;

        float4 val0, val1;
        val0.x = mk0.x ? -INFINITY : lp0.x;
        val0.y = mk0.y ? -INFINITY : lp0.y;
        val0.z = mk0.z ? -INFINITY : lp0.z;
        val0.w = mk0.w ? -INFINITY : lp0.w;
        val1.x = mk1.x ? -INFINITY : lp1.x;
        val1.y = mk1.y ? -INFINITY : lp1.y;
        val1.z = mk1.z ? -INFINITY : lp1.z;
        val1.w = mk1.w ? -INFINITY : lp1.w;
        if (!has1) val1 = make_float4(-INFINITY, -INFINITY, -INFINITY, -INFINITY);

        float m2 = fmaxf(fmaxf(fmaxf(val0.x, val0.y), fmaxf(val0.z, val0.w)),
                         fmaxf(fmaxf(val1.x, val1.y), fmaxf(val1.z, val1.w)));
#pragma unroll
        for (int o = 32; o >= 1; o >>= 1) m2 = fmaxf(m2, __shfl_xor(m2, o));

        float4 e0, e1;
        e0.x = __expf(val0.x - m2); e0.y = __expf(val0.y - m2);
        e0.z = __expf(val0.z - m2); e0.w = __expf(val0.w - m2);
        e1.x = __expf(val1.x - m2); e1.y = __expf(val1.y - m2);
        e1.z = __expf(val1.z - m2); e1.w = __expf(val1.w - m2);
        float sum2 = e0.x + e0.y + e0.z + e0.w + e1.x + e1.y + e1.z + e1.w;
#pragma unroll
        for (int o = 32; o >= 1; o >>= 1) sum2 += __shfl_xor(sum2, o);
        float inv = 1.f / sum2;

        float4 a0, a1;
        a0.x = e0.x * inv; a0.y = e0.y * inv; a0.z = e0.z * inv; a0.w = e0.w * inv;
        a1.x = e1.x * inv; a1.y = e1.y * inv; a1.z = e1.z * inv; a1.w = e1.w * inv;
        *(float4*)&atout[s0i] = a0;
        if (has1) *(float4*)&atout[s1i] = a1;
    }
}

// ---------------------------------------------------------------------------
extern "C" void kernel_launch(void* const* d_in, const int* in_sizes, int n_in,
                              void* d_out, int out_size, void* d_ws, size_t ws_size,
                              hipStream_t stream)
{
    (void)in_sizes; (void)n_in; (void)out_size; (void)ws_size;

    const float* queries = (const float*)d_in[0];
    const float* keys    = (const float*)d_in[1];
    const float* prior   = (const float*)d_in[2];
    const int*   mask    = (const int*)d_in[3];
    const float* kw1     = (const float*)d_in[4];
    const float* kb1     = (const float*)d_in[5];
    const float* kw2     = (const float*)d_in[6];
    const float* kb2     = (const float*)d_in[7];
    const float* qw1     = (const float*)d_in[8];
    const float* qb1     = (const float*)d_in[9];
    const float* qw2     = (const float*)d_in[10];
    const float* qb2     = (const float*)d_in[11];
    const float* qw3     = (const float*)d_in[12];
    const float* qb3     = (const float*)d_in[13];

    unsigned short* U = (unsigned short*)d_ws;
    unsigned short* K1t = U;                        // [12800][1024]
    unsigned short* Q1t = U;                        // [51200][160] (reuse)
    unsigned short* Xk  = U + 13107200;             // [13058][512]
    unsigned short* Qt  = U + 13107200;             // [51200][96] (reuse after key path)
    unsigned short* Xq  = U + 19792896;             // [51458][96]
    unsigned short* Kt  = U + 24732864;             // [12800][96]
    unsigned short* Wk1 = U + 25961664;             // 3*1024*512
    unsigned short* Wk2 = U + 27534528;             // 128*1024
    unsigned short* Wq1 = U + 27665600;             // 3*256*96
    unsigned short* Wq2 = U + 27739328;             // 128*160
    unsigned short* Wq3 = U + 27759808;             // 128*96
    float*          k2s = (float*)(U + 27772096);   // 12800 f32

    float* out_attn = (float*)d_out;
    float* out_lp   = out_attn + (size_t)32 * 1600 * 400;

    // 1) all prep
    prep_all<<<NKB + NQB + NFB, dim3(256), 0, stream>>>(
        keys, queries, kw1, kw2, qw1, qw2, qw3,
        Xk, Xq, Wk1, Wk2, Wq1, Wq2, Wq3);

    // 2) both 3-tap convs (key 408 + q 402, balanced per XCD)
    conv1_both<<<810, dim3(512), 0, stream>>>(
        Wk1, Xk, kb1, K1t, Wq1, Xq, qb1, Q1t);

    // 3) key conv2 (+k2) || q conv2+conv3 fused
    conv2_both<<<500, dim3(256), 0, stream>>>(
        Wk2, K1t, kb2, Kt, k2s, Wq2, Wq3, qb2, qb3, Q1t, Qt);

    // 4) fused attention + softmaxes (float4 I/O)
    attn_v2<<<dim3(50, 32), dim3(512), 0, stream>>>(
        Kt, Qt, k2s, prior, mask, out_attn, out_lp);
}

// Round 15
// 220.397 us; speedup vs baseline: 1.2407x; 1.0082x over previous
//
#include <hip/hip_runtime.h>
#include <math.h>

// ---------------------------------------------------------------------------
// ConvAttention (B=32, T1=1600, T2=400, n_mel=80, n_text=512, n_att=80)
// Round 14: revert conv1_both to r12 (128x256, vmcnt(3), balanced per-range
//   XCD swizzle, T2 chunk swizzle — 96us proven; r13's 256² tile regressed
//   from 2-blocks/CU occupancy + grid tail). NEW: attn_v2 memory ops
//   vectorized to float4 via s = lane*4 + 256*j lane mapping (G13).
// ---------------------------------------------------------------------------

typedef __attribute__((ext_vector_type(8))) short bf16x8;
typedef __attribute__((ext_vector_type(4))) float f32x4;

static __device__ __forceinline__ unsigned short f2bf(float f) {
    union { float f; unsigned u; } v; v.f = f;
    unsigned r = v.u + 0x7FFF + ((v.u >> 16) & 1);
    return (unsigned short)(r >> 16);
}
static __device__ __forceinline__ float bf2f(unsigned short h) {
    union { unsigned u; float f; } v; v.u = ((unsigned)h) << 16;
    return v.f;
}

#define GLOAD16(g, s) __builtin_amdgcn_global_load_lds( \
    (const __attribute__((address_space(1))) void*)(g), \
    (__attribute__((address_space(3))) void*)(s), 16, 0, 0)

// ---------------- kernel 1: all prep ----------------
static __device__ __forceinline__ void fill_w(
    const float* __restrict__ w, unsigned short* __restrict__ dst, int rem,
    int Cout, int Cin, int KTAP, int CoutAlloc, int CinPad)
{
    int d  = rem / (CoutAlloc * CinPad);
    int r2 = rem - d * (CoutAlloc * CinPad);
    int co = r2 / CinPad, ci = r2 - co * CinPad;
    float v = (co < Cout && ci < Cin) ? w[((size_t)co * Cin + ci) * KTAP + d] : 0.f;
    dst[rem] = f2bf(v);
}

#define S0 1572864       // Wk1 3*1024*512
#define S1 (S0+131072)   // Wk2 128*1024
#define S2 (S1+73728)    // Wq1 3*256*96
#define S3 (S2+20480)    // Wq2 128*160
#define S4 (S3+12288)    // Wq3 128*96
#define S5 (S4+66560)    // Xk tail 130*512
#define S6 (S5+12480)    // Xq tail 130*96
#define NKB 6656         // 13*16*32 key transpose blocks
#define NQB 4896         // 51*3*32  query transpose blocks
#define NFB ((S6+255)/256)

static __device__ __forceinline__ void transpose_body(
    const float* __restrict__ in, unsigned short* __restrict__ Xt,
    int C, int CinPad, int T, int Trow,
    int bx, int by, int bz, float s[32][33])
{
    int ci0 = by * 32, tr0 = bx * 32;
    int tx = threadIdx.x & 31, ty = threadIdx.x >> 5;
#pragma unroll
    for (int i = 0; i < 4; i++) {
        int c = ci0 + ty + 8 * i;
        int t_in = tr0 + tx - 1;
        float v = (c < C && t_in >= 0 && t_in < T)
                    ? in[((size_t)bz * C + c) * T + t_in] : 0.f;
        s[ty + 8 * i][tx] = v;
    }
    __syncthreads();
#pragma unroll
    for (int i = 0; i < 4; i++) {
        int tr = tr0 + ty + 8 * i;
        if (tr < Trow)
            Xt[((size_t)bz * Trow + tr) * CinPad + ci0 + tx] = f2bf(s[tx][ty + 8 * i]);
    }
}

__global__ __launch_bounds__(256) void prep_all(
    const float* __restrict__ keys, const float* __restrict__ queries,
    const float* __restrict__ kw1, const float* __restrict__ kw2,
    const float* __restrict__ qw1, const float* __restrict__ qw2,
    const float* __restrict__ qw3,
    unsigned short* __restrict__ Xk, unsigned short* __restrict__ Xq,
    unsigned short* __restrict__ Wk1, unsigned short* __restrict__ Wk2,
    unsigned short* __restrict__ Wq1, unsigned short* __restrict__ Wq2,
    unsigned short* __restrict__ Wq3)
{
    __shared__ float s[32][33];
    int bxg = blockIdx.x;
    if (bxg < NKB) {
        int x = bxg % 13, y = (bxg / 13) & 15, z = bxg / (13 * 16);
        transpose_body(keys, Xk, 512, 512, 400, 404, x, y, z, s);
    } else if (bxg < NKB + NQB) {
        int b2 = bxg - NKB;
        int x = b2 % 51, y = (b2 / 51) % 3, z = b2 / 153;
        transpose_body(queries, Xq, 80, 96, 1600, 1604, x, y, z, s);
    } else {
        int idx = (bxg - NKB - NQB) * 256 + threadIdx.x;
        if (idx < S0)      fill_w(kw1, Wk1, idx,       1024, 512, 3, 1024, 512);
        else if (idx < S1) fill_w(kw2, Wk2, idx - S0,  80, 1024, 1, 128, 1024);
        else if (idx < S2) fill_w(qw1, Wq1, idx - S1,  160, 80, 3, 256, 96);
        else if (idx < S3) fill_w(qw2, Wq2, idx - S2,  80, 160, 1, 128, 160);
        else if (idx < S4) fill_w(qw3, Wq3, idx - S3,  80, 80, 1, 128, 96);
        else if (idx < S5) Xk[(size_t)12928 * 512 + (idx - S4)] = 0;
        else if (idx < S6) Xq[(size_t)51328 * 96  + (idx - S5)] = 0;
    }
}

// ---------------- kernel 2: both 3-tap convs (128x256, counted vmcnt) -------
__global__ __launch_bounds__(512) void conv1_both(
    const unsigned short* __restrict__ Wk1, const unsigned short* __restrict__ Xk,
    const float* __restrict__ kb1, unsigned short* __restrict__ K1t,
    const unsigned short* __restrict__ Wq1, const unsigned short* __restrict__ Xq,
    const float* __restrict__ qb1, unsigned short* __restrict__ Q1t)
{
    constexpr int TRW = 136;
    __shared__ unsigned short lds[24576]; // 2 bufs x (A[128][32] + B[256][32])

    const int tid  = threadIdx.x;
    const int lane = tid & 63;
    const int wid  = tid >> 6;
    const int wm   = wid >> 2;
    const int wn   = wid & 3;

    const int bid = blockIdx.x;
    const unsigned short* Wbf; const unsigned short* Xt;
    const float* bias; unsigned short* out;
    int CinPad, CoutAlloc, Cout, Trow, Tout, OutStride, nCo, Nvalid, wgid;
    if (bid < 408) {
        int xcd = bid & 7, ix = bid >> 3;
        wgid = xcd * 51 + ix;
        Wbf = Wk1; Xt = Xk; bias = kb1; out = K1t;
        CinPad = 512; CoutAlloc = 1024; Cout = 1024; Trow = 404; Tout = 400;
        OutStride = 1024; nCo = 8; Nvalid = 12928;
    } else {
        int b2 = bid - 408;
        int xcd = b2 & 7, ix = b2 >> 3;
        wgid = (xcd < 2 ? xcd * 51 : 2 * 51 + (xcd - 2) * 50) + ix;
        Wbf = Wq1; Xt = Xq; bias = qb1; out = Q1t;
        CinPad = 96; CoutAlloc = 256; Cout = 160; Trow = 1604; Tout = 1600;
        OutStride = 160; nCo = 2; Nvalid = 51328;
    }
    const int co0 = (wgid % nCo) * 128;
    const int n0  = (wgid / nCo) * 256;

    const int lr = lane >> 2;
    const int fr = lane & 15;
    // T2 chunk swizzle (r12): slot (row,c) holds global chunk c ^ ((row&15)>>1 & 3)
    const int lc = (((lane & 3) ^ ((lr >> 1) & 3)) * 8);
    const int ko = (((lane >> 4) ^ ((fr >> 1) & 3)) * 8);

    const int nKc   = CinPad >> 5;
    const int nIter = 3 * nKc;

    f32x4 a4[4][4] = {};

    int scc = 0, sd = 0;
#define STAGE(B)                                                                  \
    {                                                                             \
        const unsigned short* asrc =                                              \
            Wbf + ((size_t)sd * CoutAlloc + co0 + wid * 16 + lr) * CinPad + scc * 32 + lc; \
        const unsigned short* bsrc =                                              \
            Xt + ((size_t)(n0 + sd) + wid * 32 + lr) * CinPad + scc * 32 + lc;    \
        unsigned short* Ab = lds + (B) * 12288;                                   \
        GLOAD16(asrc, &Ab[wid * 512]);                                            \
        GLOAD16(bsrc, &Ab[4096 + wid * 1024]);                                    \
        GLOAD16(bsrc + (size_t)16 * CinPad, &Ab[4096 + wid * 1024 + 512]);        \
        scc++; if (scc == nKc) { scc = 0; sd++; }                                 \
    }

#define COMPUTE(B)                                                                \
    {                                                                             \
        const unsigned short* Ab = lds + (B) * 12288;                             \
        const unsigned short* Bb = Ab + 4096;                                     \
        bf16x8 af[4], bfr[4];                                                     \
        _Pragma("unroll")                                                         \
        for (int mi = 0; mi < 4; mi++)                                            \
            af[mi] = *(const bf16x8*)&Ab[(wm * 64 + mi * 16 + fr) * 32 + ko];     \
        _Pragma("unroll")                                                         \
        for (int ni = 0; ni < 4; ni++)                                            \
            bfr[ni] = *(const bf16x8*)&Bb[(wn * 64 + ni * 16 + fr) * 32 + ko];    \
        _Pragma("unroll")                                                         \
        for (int mi = 0; mi < 4; mi++)                                            \
            _Pragma("unroll")                                                     \
            for (int ni = 0; ni < 4; ni++)                                        \
                a4[mi][ni] = __builtin_amdgcn_mfma_f32_16x16x32_bf16(             \
                    af[mi], bfr[ni], a4[mi][ni], 0, 0, 0);                        \
    }

    STAGE(0);
    STAGE(1);

    for (int t = 0; t < nIter; t++) {
        if (t < nIter - 1)
            asm volatile("s_waitcnt vmcnt(3)" ::: "memory");
        else
            asm volatile("s_waitcnt vmcnt(0)" ::: "memory");
        __builtin_amdgcn_s_barrier();
        COMPUTE(t & 1);
        __builtin_amdgcn_sched_barrier(0);
        __builtin_amdgcn_s_barrier();
        if (t + 2 < nIter) STAGE(t & 1);
    }
#undef STAGE
#undef COMPUTE

    __syncthreads();

    int cw = OutStride - co0; if (cw > 128) cw = 128;
#pragma unroll
    for (int p = 0; p < 4; p++) {
        if (wn == p) {
#pragma unroll
            for (int mi = 0; mi < 4; mi++) {
                int col = wm * 64 + mi * 16 + (lane >> 4) * 4;
#pragma unroll
                for (int ni = 0; ni < 4; ni++) {
                    int row = ni * 16 + fr;
                    unsigned short pk[4];
#pragma unroll
                    for (int r = 0; r < 4; r++) {
                        int co = co0 + col + r;
                        float v = 0.f;
                        if (co < Cout) v = fmaxf(a4[mi][ni][r] + bias[co], 0.f);
                        pk[r] = f2bf(v);
                    }
                    *(unsigned long long*)&lds[row * TRW + col] = *(unsigned long long*)pk;
                }
            }
        }
        __syncthreads();
        int row = tid >> 3;
        int c0  = (tid & 7) * 16;
        int n   = n0 + p * 64 + row;
        if (n < Nvalid && c0 < cw) {
            int b = n / Trow;
            int t = n - b * Trow;
            if (t < Tout) {
                unsigned short* dst = out + ((size_t)b * Tout + t) * OutStride + co0 + c0;
                *(bf16x8*)&dst[0] = *(const bf16x8*)&lds[row * TRW + c0];
                *(bf16x8*)&dst[8] = *(const bf16x8*)&lds[row * TRW + c0 + 8];
            }
        }
        __syncthreads();
    }
}

// ---------------- kernel 3: key conv2 (+k2) || q conv2+conv3 ----------------
__global__ __launch_bounds__(256) void conv2_both(
    const unsigned short* __restrict__ Wk2, const unsigned short* __restrict__ K1t,
    const float* __restrict__ kb2, unsigned short* __restrict__ Kt,
    float* __restrict__ k2s,
    const unsigned short* __restrict__ W2, const unsigned short* __restrict__ W3,
    const float* __restrict__ b2, const float* __restrict__ b3,
    const unsigned short* __restrict__ Q1t, unsigned short* __restrict__ Qt)
{
    constexpr int LDW = 40, TRW = 136, X2W = 104;
    __shared__ unsigned short lds[23552];
    unsigned short* Al = lds;
    unsigned short* Bl = lds + 5120;

    const int tid  = threadIdx.x;
    const int lane = tid & 63;
    const int wid  = tid >> 6;
    const int wm   = wid >> 1;
    const int wn   = wid & 1;
    const int r0 = tid >> 2;
    const int r1 = r0 + 64;
    const int q0 = (tid & 3) * 8;
    const int fr = lane & 15;
    const int ko = (lane >> 4) * 8;

    if (blockIdx.x < 100) {
        const int n0 = blockIdx.x * 128;
        f32x4 acc[4][4] = {};

        bf16x8 ra0 = *(const bf16x8*)&Wk2[(size_t)r0 * 1024 + q0];
        bf16x8 ra1 = *(const bf16x8*)&Wk2[(size_t)r1 * 1024 + q0];
        bf16x8 rb0 = *(const bf16x8*)&K1t[(size_t)(n0 + r0) * 1024 + q0];
        bf16x8 rb1 = *(const bf16x8*)&K1t[(size_t)(n0 + r1) * 1024 + q0];

        for (int kk = 0; kk < 32; kk++) {
            __syncthreads();
            *(bf16x8*)&Al[r0 * LDW + q0] = ra0;
            *(bf16x8*)&Al[r1 * LDW + q0] = ra1;
            *(bf16x8*)&Bl[r0 * LDW + q0] = rb0;
            *(bf16x8*)&Bl[r1 * LDW + q0] = rb1;
            __syncthreads();

            if (kk < 31) {
                int ci0 = (kk + 1) * 32;
                ra0 = *(const bf16x8*)&Wk2[(size_t)r0 * 1024 + ci0 + q0];
                ra1 = *(const bf16x8*)&Wk2[(size_t)r1 * 1024 + ci0 + q0];
                rb0 = *(const bf16x8*)&K1t[(size_t)(n0 + r0) * 1024 + ci0 + q0];
                rb1 = *(const bf16x8*)&K1t[(size_t)(n0 + r1) * 1024 + ci0 + q0];
            }

            bf16x8 af[4], bfr[4];
#pragma unroll
            for (int mi = 0; mi < 4; mi++)
                af[mi] = *(const bf16x8*)&Al[(wm * 64 + mi * 16 + fr) * LDW + ko];
#pragma unroll
            for (int ni = 0; ni < 4; ni++)
                bfr[ni] = *(const bf16x8*)&Bl[(wn * 64 + ni * 16 + fr) * LDW + ko];
#pragma unroll
            for (int mi = 0; mi < 4; mi++)
#pragma unroll
                for (int ni = 0; ni < 4; ni++)
                    acc[mi][ni] = __builtin_amdgcn_mfma_f32_16x16x32_bf16(
                        af[mi], bfr[ni], acc[mi][ni], 0, 0, 0);
        }

#pragma unroll
        for (int p = 0; p < 2; p++) {
            __syncthreads();
            if (wn == p) {
#pragma unroll
                for (int mi = 0; mi < 4; mi++) {
                    int col = wm * 64 + mi * 16 + (lane >> 4) * 4;
#pragma unroll
                    for (int ni = 0; ni < 4; ni++) {
                        int row = ni * 16 + fr;
                        unsigned short pk[4];
#pragma unroll
                        for (int r = 0; r < 4; r++) {
                            int co = col + r;
                            float v = 0.f;
                            if (co < 80) v = acc[mi][ni][r] + kb2[co];
                            pk[r] = f2bf(v);
                        }
                        *(unsigned long long*)&lds[row * TRW + col] = *(unsigned long long*)pk;
                    }
                }
            }
            __syncthreads();
            int rr = tid >> 2;
            int c0 = (tid & 3) * 32;
            int n  = n0 + p * 64 + rr;
            unsigned short* dst = Kt + (size_t)n * 96;
            float s = 0.f;
#pragma unroll
            for (int c = c0; c < c0 + 32; c += 8) {
                if (c < 96) {
                    bf16x8 v = *(const bf16x8*)&lds[rr * TRW + c];
                    *(bf16x8*)&dst[c] = v;
#pragma unroll
                    for (int e = 0; e < 8; e++) {
                        float f = bf2f((unsigned short)v[e]);
                        s = fmaf(f, f, s);
                    }
                }
            }
            s += __shfl_xor(s, 1);
            s += __shfl_xor(s, 2);
            if ((tid & 3) == 0) k2s[n] = s;
        }
    } else {
        unsigned short* X2 = lds + 10240;
        const int n0 = (blockIdx.x - 100) * 128;

        f32x4 acc[4][4] = {};

        bf16x8 ra0 = *(const bf16x8*)&W2[(size_t)r0 * 160 + q0];
        bf16x8 ra1 = *(const bf16x8*)&W2[(size_t)r1 * 160 + q0];
        bf16x8 rb0 = *(const bf16x8*)&Q1t[(size_t)(n0 + r0) * 160 + q0];
        bf16x8 rb1 = *(const bf16x8*)&Q1t[(size_t)(n0 + r1) * 160 + q0];

        for (int kk = 0; kk < 5; kk++) {
            __syncthreads();
            *(bf16x8*)&Al[r0 * LDW + q0] = ra0;
            *(bf16x8*)&Al[r1 * LDW + q0] = ra1;
            *(bf16x8*)&Bl[r0 * LDW + q0] = rb0;
            *(bf16x8*)&Bl[r1 * LDW + q0] = rb1;
            __syncthreads();

            if (kk < 4) {
                int ci0 = (kk + 1) * 32;
                ra0 = *(const bf16x8*)&W2[(size_t)r0 * 160 + ci0 + q0];
                ra1 = *(const bf16x8*)&W2[(size_t)r1 * 160 + ci0 + q0];
                rb0 = *(const bf16x8*)&Q1t[(size_t)(n0 + r0) * 160 + ci0 + q0];
                rb1 = *(const bf16x8*)&Q1t[(size_t)(n0 + r1) * 160 + ci0 + q0];
            }

            bf16x8 af[4], bfr[4];
#pragma unroll
            for (int mi = 0; mi < 4; mi++)
                af[mi] = *(const bf16x8*)&Al[(wm * 64 + mi * 16 + fr) * LDW + ko];
#pragma unroll
            for (int ni = 0; ni < 4; ni++)
                bfr[ni] = *(const bf16x8*)&Bl[(wn * 64 + ni * 16 + fr) * LDW + ko];
#pragma unroll
            for (int mi = 0; mi < 4; mi++)
#pragma unroll
                for (int ni = 0; ni < 4; ni++)
                    acc[mi][ni] = __builtin_amdgcn_mfma_f32_16x16x32_bf16(
                        af[mi], bfr[ni], acc[mi][ni], 0, 0, 0);
        }

#pragma unroll
        for (int mi = 0; mi < 4; mi++) {
            int col = wm * 64 + mi * 16 + (lane >> 4) * 4;
            if (col >= 96) continue;
#pragma unroll
            for (int ni = 0; ni < 4; ni++) {
                int row = wn * 64 + ni * 16 + fr;
                unsigned short pk[4];
#pragma unroll
                for (int r = 0; r < 4; r++) {
                    int co = col + r;
                    float v = 0.f;
                    if (co < 80) v = fmaxf(acc[mi][ni][r] + b2[co], 0.f);
                    pk[r] = f2bf(v);
                }
                *(unsigned long long*)&X2[row * X2W + col] = *(unsigned long long*)pk;
            }
        }

#pragma unroll
        for (int mi = 0; mi < 4; mi++)
#pragma unroll
            for (int ni = 0; ni < 4; ni++)
                acc[mi][ni] = (f32x4){0.f, 0.f, 0.f, 0.f};

        ra0 = *(const bf16x8*)&W3[(size_t)r0 * 96 + q0];
        ra1 = *(const bf16x8*)&W3[(size_t)r1 * 96 + q0];

        for (int kk = 0; kk < 3; kk++) {
            __syncthreads();
            *(bf16x8*)&Al[r0 * LDW + q0] = ra0;
            *(bf16x8*)&Al[r1 * LDW + q0] = ra1;
            __syncthreads();

            if (kk < 2) {
                int ci0 = (kk + 1) * 32;
                ra0 = *(const bf16x8*)&W3[(size_t)r0 * 96 + ci0 + q0];
                ra1 = *(const bf16x8*)&W3[(size_t)r1 * 96 + ci0 + q0];
            }

            bf16x8 af[4], bfr[4];
#pragma unroll
            for (int mi = 0; mi < 4; mi++)
                af[mi] = *(const bf16x8*)&Al[(wm * 64 + mi * 16 + fr) * LDW + ko];
#pragma unroll
            for (int ni = 0; ni < 4; ni++)
                bfr[ni] = *(const bf16x8*)&X2[(wn * 64 + ni * 16 + fr) * X2W + kk * 32 + ko];
#pragma unroll
            for (int mi = 0; mi < 4; mi++)
#pragma unroll
                for (int ni = 0; ni < 4; ni++)
                    acc[mi][ni] = __builtin_amdgcn_mfma_f32_16x16x32_bf16(
                        af[mi], bfr[ni], acc[mi][ni], 0, 0, 0);
        }

#pragma unroll
        for (int p = 0; p < 2; p++) {
            __syncthreads();
            if (wn == p) {
#pragma unroll
                for (int mi = 0; mi < 4; mi++) {
                    int col = wm * 64 + mi * 16 + (lane >> 4) * 4;
#pragma unroll
                    for (int ni = 0; ni < 4; ni++) {
                        int row = ni * 16 + fr;
                        unsigned short pk[4];
#pragma unroll
                        for (int r = 0; r < 4; r++) {
                            int co = col + r;
                            float v = 0.f;
                            if (co < 80) v = acc[mi][ni][r] + b3[co];
                            pk[r] = f2bf(v);
                        }
                        *(unsigned long long*)&lds[row * TRW + col] = *(unsigned long long*)pk;
                    }
                }
            }
            __syncthreads();
            int rr = tid >> 2;
            int c0 = (tid & 3) * 32;
            int n  = n0 + p * 64 + rr;
            unsigned short* dst = Qt + (size_t)n * 96;
#pragma unroll
            for (int c = c0; c < c0 + 32; c += 8)
                if (c < 96)
                    *(bf16x8*)&dst[c] = *(const bf16x8*)&lds[rr * TRW + c];
        }
    }
}

// ---------------- kernel 4: fused MFMA-QK + softmax/logprob (float4 I/O) ----
#define SCW 404
__global__ __launch_bounds__(512) void attn_v2(
    const unsigned short* __restrict__ Kt,   // [32*400][96] bf16
    const unsigned short* __restrict__ Qt,   // [32*1600][96] bf16
    const float* __restrict__ k2s,           // [32*400]
    const float* __restrict__ prior, const int* __restrict__ mask,
    float* __restrict__ out_attn, float* __restrict__ out_lp)
{
    const int T1 = 1600, T2 = 400;
    __shared__ float Sc[32 * SCW];

    const int tid  = threadIdx.x;
    const int lane = tid & 63;
    const int wid  = tid >> 6;
    const int b    = blockIdx.y;
    const int t0   = blockIdx.x * 32;
    const int fr   = lane & 15;
    const int ko   = (lane >> 4) * 8;

    bf16x8 qf[2][3];
#pragma unroll
    for (int ts = 0; ts < 2; ts++)
#pragma unroll
        for (int kk = 0; kk < 3; kk++)
            qf[ts][kk] = *(const bf16x8*)&Qt[((size_t)b * T1 + t0 + ts * 16 + fr) * 96 + kk * 32 + ko];

    for (int st = wid; st < 25; st += 8) {
        f32x4 acc0 = {}, acc1 = {};
#pragma unroll
        for (int kk = 0; kk < 3; kk++) {
            bf16x8 kf = *(const bf16x8*)&Kt[((size_t)b * T2 + st * 16 + fr) * 96 + kk * 32 + ko];
            acc0 = __builtin_amdgcn_mfma_f32_16x16x32_bf16(kf, qf[0][kk], acc0, 0, 0, 0);
            acc1 = __builtin_amdgcn_mfma_f32_16x16x32_bf16(kf, qf[1][kk], acc1, 0, 0, 0);
        }
        int sbase = st * 16 + (lane >> 4) * 4;
        float4 kv = *(const float4*)&k2s[b * T2 + sbase];
        float4 w0, w1;
        w0.x = fmaf(1e-3f, acc0[0], -5e-4f * kv.x);
        w0.y = fmaf(1e-3f, acc0[1], -5e-4f * kv.y);
        w0.z = fmaf(1e-3f, acc0[2], -5e-4f * kv.z);
        w0.w = fmaf(1e-3f, acc0[3], -5e-4f * kv.w);
        w1.x = fmaf(1e-3f, acc1[0], -5e-4f * kv.x);
        w1.y = fmaf(1e-3f, acc1[1], -5e-4f * kv.y);
        w1.z = fmaf(1e-3f, acc1[2], -5e-4f * kv.z);
        w1.w = fmaf(1e-3f, acc1[3], -5e-4f * kv.w);
        *(float4*)&Sc[fr * SCW + sbase]        = w0;
        *(float4*)&Sc[(16 + fr) * SCW + sbase] = w1;
    }

    // lane -> s mapping: s = lane*4 + 256*j ; j=0 lanes 0..63, j=1 lanes 0..35
    const int s0i = lane * 4;
    const int s1i = 256 + lane * 4;
    const bool has1 = (lane < 36);

    int4 mk0 = *(const int4*)&mask[b * T2 + s0i];
    int4 mk1 = has1 ? *(const int4*)&mask[b * T2 + s1i] : make_int4(1, 1, 1, 1);

    __syncthreads();

    for (int r = 0; r < 4; r++) {
        int tloc = wid * 4 + r;
        int t = t0 + tloc;

        float4 v0 = *(const float4*)&Sc[tloc * SCW + s0i];
        float4 v1;
        if (has1) v1 = *(const float4*)&Sc[tloc * SCW + s1i];
        else      v1 = make_float4(-INFINITY, -INFINITY, -INFINITY, -INFINITY);

        float m = fmaxf(fmaxf(fmaxf(v0.x, v0.y), fmaxf(v0.z, v0.w)),
                        fmaxf(fmaxf(v1.x, v1.y), fmaxf(v1.z, v1.w)));
#pragma unroll
        for (int o = 32; o >= 1; o >>= 1) m = fmaxf(m, __shfl_xor(m, o));

        float sum = __expf(v0.x - m) + __expf(v0.y - m) + __expf(v0.z - m) + __expf(v0.w - m)
                  + __expf(v1.x - m) + __expf(v1.y - m) + __expf(v1.z - m) + __expf(v1.w - m);
#pragma unroll
        for (int o = 32; o >= 1; o >>= 1) sum += __shfl_xor(sum, o);
        float lse = m + __logf(sum);

        const float* pr = prior + ((size_t)b * T1 + t) * T2;
        float* lpout = out_lp + ((size_t)b * T1 + t) * T2;
        float* atout = out_attn + ((size_t)b * T1 + t) * T2;

        float4 p0 = *(const float4*)&pr[s0i];
        float4 p1 = has1 ? *(const float4*)&pr[s1i] : make_float4(0, 0, 0, 0);

        float4 lp0, lp1;
        lp0.x = v0.x - lse + __logf(p0.x + 1e-8f);
        lp0.y = v0.y - lse + __logf(p0.y + 1e-8f);
        lp0.z = v0.z - lse + __logf(p0.z + 1e-8f);
        lp0.w = v0.w - lse + __logf(p0.w + 1e-8f);
        lp1.x = v1.x - lse + __logf(p1.x + 1e-8f);
        lp1.y = v1.y - lse + __logf(p1.y + 1e-8f);
        lp1.z = v1.z - lse + __logf(p1.z + 1e-8f);
        lp1.w = v1.w - lse + __logf(p1.w + 1e-8f);

        *(float4*)&lpout[s0i] = lp0;
        if (has1) *(float4*)&lpout[s1i] = lp1;

        float4 val0, val1;
        val0.x = mk0.x ? -INFINITY : lp0.x;
        val0.y = mk0.y ? -INFINITY : lp0.y;
        val0.z = mk0.z ? -INFINITY : lp0.z;
        val0.w = mk0.w ? -INFINITY : lp0.w;
        val1.x = mk1.x ? -INFINITY : lp1.x;
        val1.y = mk1.y ? -INFINITY : lp1.y;
        val1.z = mk1.z ? -INFINITY : lp1.z;
        val1.w = mk1.w ? -INFINITY : lp1.w;
        if (!has1) val1 = make_float4(-INFINITY, -INFINITY, -INFINITY, -INFINITY);

        float m2 = fmaxf(fmaxf(fmaxf(val0.x, val0.y), fmaxf(val0.z, val0.w)),
                         fmaxf(fmaxf(val1.x, val1.y), fmaxf(val1.z, val1.w)));
#pragma unroll
        for (int o = 32; o >= 1; o >>= 1) m2 = fmaxf(m2, __shfl_xor(m2, o));

        float4 e0, e1;
        e0.x = __expf(val0.x - m2); e0.y = __expf(val0.y - m2);
        e0.z = __expf(val0.z - m2); e0.w = __expf(val0.w - m2);
        e1.x = __expf(val1.x - m2); e1.y = __expf(val1.y - m2);
        e1.z = __expf(val1.z - m2); e1.w = __expf(val1.w - m2);
        float sum2 = e0.x + e0.y + e0.z + e0.w + e1.x + e1.y + e1.z + e1.w;
#pragma unroll
        for (int o = 32; o >= 1; o >>= 1) sum2 += __shfl_xor(sum2, o);
        float inv = 1.f / sum2;

        float4 a0, a1;
        a0.x = e0.x * inv; a0.y = e0.y * inv; a0.z = e0.z * inv; a0.w = e0.w * inv;
        a1.x = e1.x * inv; a1.y = e1.y * inv; a1.z = e1.z * inv; a1.w = e1.w * inv;
        *(float4*)&atout[s0i] = a0;
        if (has1) *(float4*)&atout[s1i] = a1;
    }
}

// ---------------------------------------------------------------------------
extern "C" void kernel_launch(void* const* d_in, const int* in_sizes, int n_in,
                              void* d_out, int out_size, void* d_ws, size_t ws_size,
                              hipStream_t stream)
{
    (void)in_sizes; (void)n_in; (void)out_size; (void)ws_size;

    const float* queries = (const float*)d_in[0];
    const float* keys    = (const float*)d_in[1];
    const float* prior   = (const float*)d_in[2];
    const int*   mask    = (const int*)d_in[3];
    const float* kw1     = (const float*)d_in[4];
    const float* kb1     = (const float*)d_in[5];
    const float* kw2     = (const float*)d_in[6];
    const float* kb2     = (const float*)d_in[7];
    const float* qw1     = (const float*)d_in[8];
    const float* qb1     = (const float*)d_in[9];
    const float* qw2     = (const float*)d_in[10];
    const float* qb2     = (const float*)d_in[11];
    const float* qw3     = (const float*)d_in[12];
    const float* qb3     = (const float*)d_in[13];

    unsigned short* U = (unsigned short*)d_ws;
    unsigned short* K1t = U;                        // [12800][1024]
    unsigned short* Q1t = U;                        // [51200][160] (reuse)
    unsigned short* Xk  = U + 13107200;             // [13058][512]
    unsigned short* Qt  = U + 13107200;             // [51200][96] (reuse after key path)
    unsigned short* Xq  = U + 19792896;             // [51458][96]
    unsigned short* Kt  = U + 24732864;             // [12800][96]
    unsigned short* Wk1 = U + 25961664;             // 3*1024*512
    unsigned short* Wk2 = U + 27534528;             // 128*1024
    unsigned short* Wq1 = U + 27665600;             // 3*256*96
    unsigned short* Wq2 = U + 27739328;             // 128*160
    unsigned short* Wq3 = U + 27759808;             // 128*96
    float*          k2s = (float*)(U + 27772096);   // 12800 f32

    float* out_attn = (float*)d_out;
    float* out_lp   = out_attn + (size_t)32 * 1600 * 400;

    // 1) all prep
    prep_all<<<NKB + NQB + NFB, dim3(256), 0, stream>>>(
        keys, queries, kw1, kw2, qw1, qw2, qw3,
        Xk, Xq, Wk1, Wk2, Wq1, Wq2, Wq3);

    // 2) both 3-tap convs (key 408 + q 402, balanced per XCD)
    conv1_both<<<810, dim3(512), 0, stream>>>(
        Wk1, Xk, kb1, K1t, Wq1, Xq, qb1, Q1t);

    // 3) key conv2 (+k2) || q conv2+conv3 fused
    conv2_both<<<500, dim3(256), 0, stream>>>(
        Wk2, K1t, kb2, Kt, k2s, Wq2, Wq3, qb2, qb3, Q1t, Qt);

    // 4) fused attention + softmaxes (float4 I/O)
    attn_v2<<<dim3(50, 32), dim3(512), 0, stream>>>(
        Kt, Qt, k2s, prior, mask, out_attn, out_lp);
}

// Round 16
// 216.377 us; speedup vs baseline: 1.2637x; 1.0186x over previous
//
#include <hip/hip_runtime.h>
#include <math.h>

// ---------------------------------------------------------------------------
// ConvAttention (B=32, T1=1600, T2=400, n_mel=80, n_text=512, n_att=80)
// Round 16 (from r15): two mechanism-backed fixes:
//   1) conv1_both: remove sched_barrier(0) from the K-loop (m141: order
//      pinning defeats compiler scheduling; correctness held by lgkmcnt
//      before MFMA + next-iter vmcnt(3)).
//   2) prep_all transpose: vectorized 16B bf16x8 writes (was 2B/lane scalar).
// ---------------------------------------------------------------------------

typedef __attribute__((ext_vector_type(8))) short bf16x8;
typedef __attribute__((ext_vector_type(4))) float f32x4;

static __device__ __forceinline__ unsigned short f2bf(float f) {
    union { float f; unsigned u; } v; v.f = f;
    unsigned r = v.u + 0x7FFF + ((v.u >> 16) & 1);
    return (unsigned short)(r >> 16);
}
static __device__ __forceinline__ float bf2f(unsigned short h) {
    union { unsigned u; float f; } v; v.u = ((unsigned)h) << 16;
    return v.f;
}

#define GLOAD16(g, s) __builtin_amdgcn_global_load_lds( \
    (const __attribute__((address_space(1))) void*)(g), \
    (__attribute__((address_space(3))) void*)(s), 16, 0, 0)

// ---------------- kernel 1: all prep ----------------
static __device__ __forceinline__ void fill_w(
    const float* __restrict__ w, unsigned short* __restrict__ dst, int rem,
    int Cout, int Cin, int KTAP, int CoutAlloc, int CinPad)
{
    int d  = rem / (CoutAlloc * CinPad);
    int r2 = rem - d * (CoutAlloc * CinPad);
    int co = r2 / CinPad, ci = r2 - co * CinPad;
    float v = (co < Cout && ci < Cin) ? w[((size_t)co * Cin + ci) * KTAP + d] : 0.f;
    dst[rem] = f2bf(v);
}

#define S0 1572864       // Wk1 3*1024*512
#define S1 (S0+131072)   // Wk2 128*1024
#define S2 (S1+73728)    // Wq1 3*256*96
#define S3 (S2+20480)    // Wq2 128*160
#define S4 (S3+12288)    // Wq3 128*96
#define S5 (S4+66560)    // Xk tail 130*512
#define S6 (S5+12480)    // Xq tail 130*96
#define NKB 6656         // 13*16*32 key transpose blocks
#define NQB 4896         // 51*3*32  query transpose blocks
#define NFB ((S6+255)/256)

static __device__ __forceinline__ void transpose_body(
    const float* __restrict__ in, unsigned short* __restrict__ Xt,
    int C, int CinPad, int T, int Trow,
    int bx, int by, int bz, float s[32][33])
{
    int ci0 = by * 32, tr0 = bx * 32;
    int tx = threadIdx.x & 31, ty = threadIdx.x >> 5;
#pragma unroll
    for (int i = 0; i < 4; i++) {
        int c = ci0 + ty + 8 * i;
        int t_in = tr0 + tx - 1;
        float v = (c < C && t_in >= 0 && t_in < T)
                    ? in[((size_t)bz * C + c) * T + t_in] : 0.f;
        s[ty + 8 * i][tx] = v;
    }
    __syncthreads();
    // vectorized write: 128 lanes x 16B (8 ci each) cover the 32x32 tile
    if (threadIdx.x < 128) {
        int row = threadIdx.x >> 2;       // t_local 0..31
        int cq  = (threadIdx.x & 3) * 8;  // ci sub-chunk
        int tr  = tr0 + row;
        if (tr < Trow) {
            unsigned short pk[8];
#pragma unroll
            for (int e = 0; e < 8; e++) pk[e] = f2bf(s[cq + e][row]);
            *(bf16x8*)&Xt[((size_t)bz * Trow + tr) * CinPad + ci0 + cq] =
                *(const bf16x8*)pk;
        }
    }
}

__global__ __launch_bounds__(256) void prep_all(
    const float* __restrict__ keys, const float* __restrict__ queries,
    const float* __restrict__ kw1, const float* __restrict__ kw2,
    const float* __restrict__ qw1, const float* __restrict__ qw2,
    const float* __restrict__ qw3,
    unsigned short* __restrict__ Xk, unsigned short* __restrict__ Xq,
    unsigned short* __restrict__ Wk1, unsigned short* __restrict__ Wk2,
    unsigned short* __restrict__ Wq1, unsigned short* __restrict__ Wq2,
    unsigned short* __restrict__ Wq3)
{
    __shared__ float s[32][33];
    int bxg = blockIdx.x;
    if (bxg < NKB) {
        int x = bxg % 13, y = (bxg / 13) & 15, z = bxg / (13 * 16);
        transpose_body(keys, Xk, 512, 512, 400, 404, x, y, z, s);
    } else if (bxg < NKB + NQB) {
        int b2 = bxg - NKB;
        int x = b2 % 51, y = (b2 / 51) % 3, z = b2 / 153;
        transpose_body(queries, Xq, 80, 96, 1600, 1604, x, y, z, s);
    } else {
        int idx = (bxg - NKB - NQB) * 256 + threadIdx.x;
        if (idx < S0)      fill_w(kw1, Wk1, idx,       1024, 512, 3, 1024, 512);
        else if (idx < S1) fill_w(kw2, Wk2, idx - S0,  80, 1024, 1, 128, 1024);
        else if (idx < S2) fill_w(qw1, Wq1, idx - S1,  160, 80, 3, 256, 96);
        else if (idx < S3) fill_w(qw2, Wq2, idx - S2,  80, 160, 1, 128, 160);
        else if (idx < S4) fill_w(qw3, Wq3, idx - S3,  80, 80, 1, 128, 96);
        else if (idx < S5) Xk[(size_t)12928 * 512 + (idx - S4)] = 0;
        else if (idx < S6) Xq[(size_t)51328 * 96  + (idx - S5)] = 0;
    }
}

// ---------------- kernel 2: both 3-tap convs (128x256, counted vmcnt) -------
__global__ __launch_bounds__(512) void conv1_both(
    const unsigned short* __restrict__ Wk1, const unsigned short* __restrict__ Xk,
    const float* __restrict__ kb1, unsigned short* __restrict__ K1t,
    const unsigned short* __restrict__ Wq1, const unsigned short* __restrict__ Xq,
    const float* __restrict__ qb1, unsigned short* __restrict__ Q1t)
{
    constexpr int TRW = 136;
    __shared__ unsigned short lds[24576]; // 2 bufs x (A[128][32] + B[256][32])

    const int tid  = threadIdx.x;
    const int lane = tid & 63;
    const int wid  = tid >> 6;
    const int wm   = wid >> 2;
    const int wn   = wid & 3;

    const int bid = blockIdx.x;
    const unsigned short* Wbf; const unsigned short* Xt;
    const float* bias; unsigned short* out;
    int CinPad, CoutAlloc, Cout, Trow, Tout, OutStride, nCo, Nvalid, wgid;
    if (bid < 408) {
        int xcd = bid & 7, ix = bid >> 3;
        wgid = xcd * 51 + ix;
        Wbf = Wk1; Xt = Xk; bias = kb1; out = K1t;
        CinPad = 512; CoutAlloc = 1024; Cout = 1024; Trow = 404; Tout = 400;
        OutStride = 1024; nCo = 8; Nvalid = 12928;
    } else {
        int b2 = bid - 408;
        int xcd = b2 & 7, ix = b2 >> 3;
        wgid = (xcd < 2 ? xcd * 51 : 2 * 51 + (xcd - 2) * 50) + ix;
        Wbf = Wq1; Xt = Xq; bias = qb1; out = Q1t;
        CinPad = 96; CoutAlloc = 256; Cout = 160; Trow = 1604; Tout = 1600;
        OutStride = 160; nCo = 2; Nvalid = 51328;
    }
    const int co0 = (wgid % nCo) * 128;
    const int n0  = (wgid / nCo) * 256;

    const int lr = lane >> 2;
    const int fr = lane & 15;
    // T2 chunk swizzle (r12): slot (row,c) holds global chunk c ^ ((row&15)>>1 & 3)
    const int lc = (((lane & 3) ^ ((lr >> 1) & 3)) * 8);
    const int ko = (((lane >> 4) ^ ((fr >> 1) & 3)) * 8);

    const int nKc   = CinPad >> 5;
    const int nIter = 3 * nKc;

    f32x4 a4[4][4] = {};

    int scc = 0, sd = 0;
#define STAGE(B)                                                                  \
    {                                                                             \
        const unsigned short* asrc =                                              \
            Wbf + ((size_t)sd * CoutAlloc + co0 + wid * 16 + lr) * CinPad + scc * 32 + lc; \
        const unsigned short* bsrc =                                              \
            Xt + ((size_t)(n0 + sd) + wid * 32 + lr) * CinPad + scc * 32 + lc;    \
        unsigned short* Ab = lds + (B) * 12288;                                   \
        GLOAD16(asrc, &Ab[wid * 512]);                                            \
        GLOAD16(bsrc, &Ab[4096 + wid * 1024]);                                    \
        GLOAD16(bsrc + (size_t)16 * CinPad, &Ab[4096 + wid * 1024 + 512]);        \
        scc++; if (scc == nKc) { scc = 0; sd++; }                                 \
    }

#define COMPUTE(B)                                                                \
    {                                                                             \
        const unsigned short* Ab = lds + (B) * 12288;                             \
        const unsigned short* Bb = Ab + 4096;                                     \
        bf16x8 af[4], bfr[4];                                                     \
        _Pragma("unroll")                                                         \
        for (int mi = 0; mi < 4; mi++)                                            \
            af[mi] = *(const bf16x8*)&Ab[(wm * 64 + mi * 16 + fr) * 32 + ko];     \
        _Pragma("unroll")                                                         \
        for (int ni = 0; ni < 4; ni++)                                            \
            bfr[ni] = *(const bf16x8*)&Bb[(wn * 64 + ni * 16 + fr) * 32 + ko];    \
        _Pragma("unroll")                                                         \
        for (int mi = 0; mi < 4; mi++)                                            \
            _Pragma("unroll")                                                     \
            for (int ni = 0; ni < 4; ni++)                                        \
                a4[mi][ni] = __builtin_amdgcn_mfma_f32_16x16x32_bf16(             \
                    af[mi], bfr[ni], a4[mi][ni], 0, 0, 0);                        \
    }

    STAGE(0);
    STAGE(1);

    for (int t = 0; t < nIter; t++) {
        if (t < nIter - 1)
            asm volatile("s_waitcnt vmcnt(3)" ::: "memory");
        else
            asm volatile("s_waitcnt vmcnt(0)" ::: "memory");
        __builtin_amdgcn_s_barrier();
        COMPUTE(t & 1);
        // (sched_barrier(0) removed — m141: pinning defeats compiler scheduling;
        //  ds_reads are consumed by MFMAs before the barrier, gload ordering
        //  carried by next iteration's vmcnt(3))
        __builtin_amdgcn_s_barrier();
        if (t + 2 < nIter) STAGE(t & 1);
    }
#undef STAGE
#undef COMPUTE

    __syncthreads();

    int cw = OutStride - co0; if (cw > 128) cw = 128;
#pragma unroll
    for (int p = 0; p < 4; p++) {
        if (wn == p) {
#pragma unroll
            for (int mi = 0; mi < 4; mi++) {
                int col = wm * 64 + mi * 16 + (lane >> 4) * 4;
#pragma unroll
                for (int ni = 0; ni < 4; ni++) {
                    int row = ni * 16 + fr;
                    unsigned short pk[4];
#pragma unroll
                    for (int r = 0; r < 4; r++) {
                        int co = co0 + col + r;
                        float v = 0.f;
                        if (co < Cout) v = fmaxf(a4[mi][ni][r] + bias[co], 0.f);
                        pk[r] = f2bf(v);
                    }
                    *(unsigned long long*)&lds[row * TRW + col] = *(unsigned long long*)pk;
                }
            }
        }
        __syncthreads();
        int row = tid >> 3;
        int c0  = (tid & 7) * 16;
        int n   = n0 + p * 64 + row;
        if (n < Nvalid && c0 < cw) {
            int b = n / Trow;
            int t = n - b * Trow;
            if (t < Tout) {
                unsigned short* dst = out + ((size_t)b * Tout + t) * OutStride + co0 + c0;
                *(bf16x8*)&dst[0] = *(const bf16x8*)&lds[row * TRW + c0];
                *(bf16x8*)&dst[8] = *(const bf16x8*)&lds[row * TRW + c0 + 8];
            }
        }
        __syncthreads();
    }
}

// ---------------- kernel 3: key conv2 (+k2) || q conv2+conv3 ----------------
__global__ __launch_bounds__(256) void conv2_both(
    const unsigned short* __restrict__ Wk2, const unsigned short* __restrict__ K1t,
    const float* __restrict__ kb2, unsigned short* __restrict__ Kt,
    float* __restrict__ k2s,
    const unsigned short* __restrict__ W2, const unsigned short* __restrict__ W3,
    const float* __restrict__ b2, const float* __restrict__ b3,
    const unsigned short* __restrict__ Q1t, unsigned short* __restrict__ Qt)
{
    constexpr int LDW = 40, TRW = 136, X2W = 104;
    __shared__ unsigned short lds[23552];
    unsigned short* Al = lds;
    unsigned short* Bl = lds + 5120;

    const int tid  = threadIdx.x;
    const int lane = tid & 63;
    const int wid  = tid >> 6;
    const int wm   = wid >> 1;
    const int wn   = wid & 1;
    const int r0 = tid >> 2;
    const int r1 = r0 + 64;
    const int q0 = (tid & 3) * 8;
    const int fr = lane & 15;
    const int ko = (lane >> 4) * 8;

    if (blockIdx.x < 100) {
        const int n0 = blockIdx.x * 128;
        f32x4 acc[4][4] = {};

        bf16x8 ra0 = *(const bf16x8*)&Wk2[(size_t)r0 * 1024 + q0];
        bf16x8 ra1 = *(const bf16x8*)&Wk2[(size_t)r1 * 1024 + q0];
        bf16x8 rb0 = *(const bf16x8*)&K1t[(size_t)(n0 + r0) * 1024 + q0];
        bf16x8 rb1 = *(const bf16x8*)&K1t[(size_t)(n0 + r1) * 1024 + q0];

        for (int kk = 0; kk < 32; kk++) {
            __syncthreads();
            *(bf16x8*)&Al[r0 * LDW + q0] = ra0;
            *(bf16x8*)&Al[r1 * LDW + q0] = ra1;
            *(bf16x8*)&Bl[r0 * LDW + q0] = rb0;
            *(bf16x8*)&Bl[r1 * LDW + q0] = rb1;
            __syncthreads();

            if (kk < 31) {
                int ci0 = (kk + 1) * 32;
                ra0 = *(const bf16x8*)&Wk2[(size_t)r0 * 1024 + ci0 + q0];
                ra1 = *(const bf16x8*)&Wk2[(size_t)r1 * 1024 + ci0 + q0];
                rb0 = *(const bf16x8*)&K1t[(size_t)(n0 + r0) * 1024 + ci0 + q0];
                rb1 = *(const bf16x8*)&K1t[(size_t)(n0 + r1) * 1024 + ci0 + q0];
            }

            bf16x8 af[4], bfr[4];
#pragma unroll
            for (int mi = 0; mi < 4; mi++)
                af[mi] = *(const bf16x8*)&Al[(wm * 64 + mi * 16 + fr) * LDW + ko];
#pragma unroll
            for (int ni = 0; ni < 4; ni++)
                bfr[ni] = *(const bf16x8*)&Bl[(wn * 64 + ni * 16 + fr) * LDW + ko];
#pragma unroll
            for (int mi = 0; mi < 4; mi++)
#pragma unroll
                for (int ni = 0; ni < 4; ni++)
                    acc[mi][ni] = __builtin_amdgcn_mfma_f32_16x16x32_bf16(
                        af[mi], bfr[ni], acc[mi][ni], 0, 0, 0);
        }

#pragma unroll
        for (int p = 0; p < 2; p++) {
            __syncthreads();
            if (wn == p) {
#pragma unroll
                for (int mi = 0; mi < 4; mi++) {
                    int col = wm * 64 + mi * 16 + (lane >> 4) * 4;
#pragma unroll
                    for (int ni = 0; ni < 4; ni++) {
                        int row = ni * 16 + fr;
                        unsigned short pk[4];
#pragma unroll
                        for (int r = 0; r < 4; r++) {
                            int co = col + r;
                            float v = 0.f;
                            if (co < 80) v = acc[mi][ni][r] + kb2[co];
                            pk[r] = f2bf(v);
                        }
                        *(unsigned long long*)&lds[row * TRW + col] = *(unsigned long long*)pk;
                    }
                }
            }
            __syncthreads();
            int rr = tid >> 2;
            int c0 = (tid & 3) * 32;
            int n  = n0 + p * 64 + rr;
            unsigned short* dst = Kt + (size_t)n * 96;
            float s = 0.f;
#pragma unroll
            for (int c = c0; c < c0 + 32; c += 8) {
                if (c < 96) {
                    bf16x8 v = *(const bf16x8*)&lds[rr * TRW + c];
                    *(bf16x8*)&dst[c] = v;
#pragma unroll
                    for (int e = 0; e < 8; e++) {
                        float f = bf2f((unsigned short)v[e]);
                        s = fmaf(f, f, s);
                    }
                }
            }
            s += __shfl_xor(s, 1);
            s += __shfl_xor(s, 2);
            if ((tid & 3) == 0) k2s[n] = s;
        }
    } else {
        unsigned short* X2 = lds + 10240;
        const int n0 = (blockIdx.x - 100) * 128;

        f32x4 acc[4][4] = {};

        bf16x8 ra0 = *(const bf16x8*)&W2[(size_t)r0 * 160 + q0];
        bf16x8 ra1 = *(const bf16x8*)&W2[(size_t)r1 * 160 + q0];
        bf16x8 rb0 = *(const bf16x8*)&Q1t[(size_t)(n0 + r0) * 160 + q0];
        bf16x8 rb1 = *(const bf16x8*)&Q1t[(size_t)(n0 + r1) * 160 + q0];

        for (int kk = 0; kk < 5; kk++) {
            __syncthreads();
            *(bf16x8*)&Al[r0 * LDW + q0] = ra0;
            *(bf16x8*)&Al[r1 * LDW + q0] = ra1;
            *(bf16x8*)&Bl[r0 * LDW + q0] = rb0;
            *(bf16x8*)&Bl[r1 * LDW + q0] = rb1;
            __syncthreads();

            if (kk < 4) {
                int ci0 = (kk + 1) * 32;
                ra0 = *(const bf16x8*)&W2[(size_t)r0 * 160 + ci0 + q0];
                ra1 = *(const bf16x8*)&W2[(size_t)r1 * 160 + ci0 + q0];
                rb0 = *(const bf16x8*)&Q1t[(size_t)(n0 + r0) * 160 + ci0 + q0];
                rb1 = *(const bf16x8*)&Q1t[(size_t)(n0 + r1) * 160 + ci0 + q0];
            }

            bf16x8 af[4], bfr[4];
#pragma unroll
            for (int mi = 0; mi < 4; mi++)
                af[mi] = *(const bf16x8*)&Al[(wm * 64 + mi * 16 + fr) * LDW + ko];
#pragma unroll
            for (int ni = 0; ni < 4; ni++)
                bfr[ni] = *(const bf16x8*)&Bl[(wn * 64 + ni * 16 + fr) * LDW + ko];
#pragma unroll
            for (int mi = 0; mi < 4; mi++)
#pragma unroll
                for (int ni = 0; ni < 4; ni++)
                    acc[mi][ni] = __builtin_amdgcn_mfma_f32_16x16x32_bf16(
                        af[mi], bfr[ni], acc[mi][ni], 0, 0, 0);
        }

#pragma unroll
        for (int mi = 0; mi < 4; mi++) {
            int col = wm * 64 + mi * 16 + (lane >> 4) * 4;
            if (col >= 96) continue;
#pragma unroll
            for (int ni = 0; ni < 4; ni++) {
                int row = wn * 64 + ni * 16 + fr;
                unsigned short pk[4];
#pragma unroll
                for (int r = 0; r < 4; r++) {
                    int co = col + r;
                    float v = 0.f;
                    if (co < 80) v = fmaxf(acc[mi][ni][r] + b2[co], 0.f);
                    pk[r] = f2bf(v);
                }
                *(unsigned long long*)&X2[row * X2W + col] = *(unsigned long long*)pk;
            }
        }

#pragma unroll
        for (int mi = 0; mi < 4; mi++)
#pragma unroll
            for (int ni = 0; ni < 4; ni++)
                acc[mi][ni] = (f32x4){0.f, 0.f, 0.f, 0.f};

        ra0 = *(const bf16x8*)&W3[(size_t)r0 * 96 + q0];
        ra1 = *(const bf16x8*)&W3[(size_t)r1 * 96 + q0];

        for (int kk = 0; kk < 3; kk++) {
            __syncthreads();
            *(bf16x8*)&Al[r0 * LDW + q0] = ra0;
            *(bf16x8*)&Al[r1 * LDW + q0] = ra1;
            __syncthreads();

            if (kk < 2) {
                int ci0 = (kk + 1) * 32;
                ra0 = *(const bf16x8*)&W3[(size_t)r0 * 96 + ci0 + q0];
                ra1 = *(const bf16x8*)&W3[(size_t)r1 * 96 + ci0 + q0];
            }

            bf16x8 af[4], bfr[4];
#pragma unroll
            for (int mi = 0; mi < 4; mi++)
                af[mi] = *(const bf16x8*)&Al[(wm * 64 + mi * 16 + fr) * LDW + ko];
#pragma unroll
            for (int ni = 0; ni < 4; ni++)
                bfr[ni] = *(const bf16x8*)&X2[(wn * 64 + ni * 16 + fr) * X2W + kk * 32 + ko];
#pragma unroll
            for (int mi = 0; mi < 4; mi++)
#pragma unroll
                for (int ni = 0; ni < 4; ni++)
                    acc[mi][ni] = __builtin_amdgcn_mfma_f32_16x16x32_bf16(
                        af[mi], bfr[ni], acc[mi][ni], 0, 0, 0);
        }

#pragma unroll
        for (int p = 0; p < 2; p++) {
            __syncthreads();
            if (wn == p) {
#pragma unroll
                for (int mi = 0; mi < 4; mi++) {
                    int col = wm * 64 + mi * 16 + (lane >> 4) * 4;
#pragma unroll
                    for (int ni = 0; ni < 4; ni++) {
                        int row = ni * 16 + fr;
                        unsigned short pk[4];
#pragma unroll
                        for (int r = 0; r < 4; r++) {
                            int co = col + r;
                            float v = 0.f;
                            if (co < 80) v = acc[mi][ni][r] + b3[co];
                            pk[r] = f2bf(v);
                        }
                        *(unsigned long long*)&lds[row * TRW + col] = *(unsigned long long*)pk;
                    }
                }
            }
            __syncthreads();
            int rr = tid >> 2;
            int c0 = (tid & 3) * 32;
            int n  = n0 + p * 64 + rr;
            unsigned short* dst = Qt + (size_t)n * 96;
#pragma unroll
            for (int c = c0; c < c0 + 32; c += 8)
                if (c < 96)
                    *(bf16x8*)&dst[c] = *(const bf16x8*)&lds[rr * TRW + c];
        }
    }
}

// ---------------- kernel 4: fused MFMA-QK + softmax/logprob (float4 I/O) ----
#define SCW 404
__global__ __launch_bounds__(512) void attn_v2(
    const unsigned short* __restrict__ Kt,   // [32*400][96] bf16
    const unsigned short* __restrict__ Qt,   // [32*1600][96] bf16
    const float* __restrict__ k2s,           // [32*400]
    const float* __restrict__ prior, const int* __restrict__ mask,
    float* __restrict__ out_attn, float* __restrict__ out_lp)
{
    const int T1 = 1600, T2 = 400;
    __shared__ float Sc[32 * SCW];

    const int tid  = threadIdx.x;
    const int lane = tid & 63;
    const int wid  = tid >> 6;
    const int b    = blockIdx.y;
    const int t0   = blockIdx.x * 32;
    const int fr   = lane & 15;
    const int ko   = (lane >> 4) * 8;

    bf16x8 qf[2][3];
#pragma unroll
    for (int ts = 0; ts < 2; ts++)
#pragma unroll
        for (int kk = 0; kk < 3; kk++)
            qf[ts][kk] = *(const bf16x8*)&Qt[((size_t)b * T1 + t0 + ts * 16 + fr) * 96 + kk * 32 + ko];

    for (int st = wid; st < 25; st += 8) {
        f32x4 acc0 = {}, acc1 = {};
#pragma unroll
        for (int kk = 0; kk < 3; kk++) {
            bf16x8 kf = *(const bf16x8*)&Kt[((size_t)b * T2 + st * 16 + fr) * 96 + kk * 32 + ko];
            acc0 = __builtin_amdgcn_mfma_f32_16x16x32_bf16(kf, qf[0][kk], acc0, 0, 0, 0);
            acc1 = __builtin_amdgcn_mfma_f32_16x16x32_bf16(kf, qf[1][kk], acc1, 0, 0, 0);
        }
        int sbase = st * 16 + (lane >> 4) * 4;
        float4 kv = *(const float4*)&k2s[b * T2 + sbase];
        float4 w0, w1;
        w0.x = fmaf(1e-3f, acc0[0], -5e-4f * kv.x);
        w0.y = fmaf(1e-3f, acc0[1], -5e-4f * kv.y);
        w0.z = fmaf(1e-3f, acc0[2], -5e-4f * kv.z);
        w0.w = fmaf(1e-3f, acc0[3], -5e-4f * kv.w);
        w1.x = fmaf(1e-3f, acc1[0], -5e-4f * kv.x);
        w1.y = fmaf(1e-3f, acc1[1], -5e-4f * kv.y);
        w1.z = fmaf(1e-3f, acc1[2], -5e-4f * kv.z);
        w1.w = fmaf(1e-3f, acc1[3], -5e-4f * kv.w);
        *(float4*)&Sc[fr * SCW + sbase]        = w0;
        *(float4*)&Sc[(16 + fr) * SCW + sbase] = w1;
    }

    // lane -> s mapping: s = lane*4 + 256*j ; j=0 lanes 0..63, j=1 lanes 0..35
    const int s0i = lane * 4;
    const int s1i = 256 + lane * 4;
    const bool has1 = (lane < 36);

    int4 mk0 = *(const int4*)&mask[b * T2 + s0i];
    int4 mk1 = has1 ? *(const int4*)&mask[b * T2 + s1i] : make_int4(1, 1, 1, 1);

    __syncthreads();

    for (int r = 0; r < 4; r++) {
        int tloc = wid * 4 + r;
        int t = t0 + tloc;

        float4 v0 = *(const float4*)&Sc[tloc * SCW + s0i];
        float4 v1;
        if (has1) v1 = *(const float4*)&Sc[tloc * SCW + s1i];
        else      v1 = make_float4(-INFINITY, -INFINITY, -INFINITY, -INFINITY);

        float m = fmaxf(fmaxf(fmaxf(v0.x, v0.y), fmaxf(v0.z, v0.w)),
                        fmaxf(fmaxf(v1.x, v1.y), fmaxf(v1.z, v1.w)));
#pragma unroll
        for (int o = 32; o >= 1; o >>= 1) m = fmaxf(m, __shfl_xor(m, o));

        float sum = __expf(v0.x - m) + __expf(v0.y - m) + __expf(v0.z - m) + __expf(v0.w - m)
                  + __expf(v1.x - m) + __expf(v1.y - m) + __expf(v1.z - m) + __expf(v1.w - m);
#pragma unroll
        for (int o = 32; o >= 1; o >>= 1) sum += __shfl_xor(sum, o);
        float lse = m + __logf(sum);

        const float* pr = prior + ((size_t)b * T1 + t) * T2;
        float* lpout = out_lp + ((size_t)b * T1 + t) * T2;
        float* atout = out_attn + ((size_t)b * T1 + t) * T2;

        float4 p0 = *(const float4*)&pr[s0i];
        float4 p1 = has1 ? *(const float4*)&pr[s1i] : make_float4(0, 0, 0, 0);

        float4 lp0, lp1;
        lp0.x = v0.x - lse + __logf(p0.x + 1e-8f);
        lp0.y = v0.y - lse + __logf(p0.y + 1e-8f);
        lp0.z = v0.z - lse + __logf(p0.z + 1e-8f);
        lp0.w = v0.w - lse + __logf(p0.w + 1e-8f);
        lp1.x = v1.x - lse + __logf(p1.x + 1e-8f);
        lp1.y = v1.y - lse + __logf(p1.y + 1e-8f);
        lp1.z = v1.z - lse + __logf(p1.z + 1e-8f);
        lp1.w = v1.w - lse + __logf(p1.w + 1e-8f);

        *(float4*)&lpout[s0i] = lp0;
        if (has1) *(float4*)&lpout[s1i] = lp1;

        float4 val0, val1;
        val0.x = mk0.x ? -INFINITY : lp0.x;
        val0.y = mk0.y ? -INFINITY : lp0.y;
        val0.z = mk0.z ? -INFINITY : lp0.z;
        val0.w = mk0.w ? -INFINITY : lp0.w;
        val1.x = mk1.x ? -INFINITY : lp1.x;
        val1.y = mk1.y ? -INFINITY : lp1.y;
        val1.z = mk1.z ? -INFINITY : lp1.z;
        val1.w = mk1.w ? -INFINITY : lp1.w;
        if (!has1) val1 = make_float4(-INFINITY, -INFINITY, -INFINITY, -INFINITY);

        float m2 = fmaxf(fmaxf(fmaxf(val0.x, val0.y), fmaxf(val0.z, val0.w)),
                         fmaxf(fmaxf(val1.x, val1.y), fmaxf(val1.z, val1.w)));
#pragma unroll
        for (int o = 32; o >= 1; o >>= 1) m2 = fmaxf(m2, __shfl_xor(m2, o));

        float4 e0, e1;
        e0.x = __expf(val0.x - m2); e0.y = __expf(val0.y - m2);
        e0.z = __expf(val0.z - m2); e0.w = __expf(val0.w - m2);
        e1.x = __expf(val1.x - m2); e1.y = __expf(val1.y - m2);
        e1.z = __expf(val1.z - m2); e1.w = __expf(val1.w - m2);
        float sum2 = e0.x + e0.y + e0.z + e0.w + e1.x + e1.y + e1.z + e1.w;
#pragma unroll
        for (int o = 32; o >= 1; o >>= 1) sum2 += __shfl_xor(sum2, o);
        float inv = 1.f / sum2;

        float4 a0, a1;
        a0.x = e0.x * inv; a0.y = e0.y * inv; a0.z = e0.z * inv; a0.w = e0.w * inv;
        a1.x = e1.x * inv; a1.y = e1.y * inv; a1.z = e1.z * inv; a1.w = e1.w * inv;
        *(float4*)&atout[s0i] = a0;
        if (has1) *(float4*)&atout[s1i] = a1;
    }
}

// ---------------------------------------------------------------------------
extern "C" void kernel_launch(void* const* d_in, const int* in_sizes, int n_in,
                              void* d_out, int out_size, void* d_ws, size_t ws_size,
                              hipStream_t stream)
{
    (void)in_sizes; (void)n_in; (void)out_size; (void)ws_size;

    const float* queries = (const float*)d_in[0];
    const float* keys    = (const float*)d_in[1];
    const float* prior   = (const float*)d_in[2];
    const int*   mask    = (const int*)d_in[3];
    const float* kw1     = (const float*)d_in[4];
    const float* kb1     = (const float*)d_in[5];
    const float* kw2     = (const float*)d_in[6];
    const float* kb2     = (const float*)d_in[7];
    const float* qw1     = (const float*)d_in[8];
    const float* qb1     = (const float*)d_in[9];
    const float* qw2     = (const float*)d_in[10];
    const float* qb2     = (const float*)d_in[11];
    const float* qw3     = (const float*)d_in[12];
    const float* qb3     = (const float*)d_in[13];

    unsigned short* U = (unsigned short*)d_ws;
    unsigned short* K1t = U;                        // [12800][1024]
    unsigned short* Q1t = U;                        // [51200][160] (reuse)
    unsigned short* Xk  = U + 13107200;             // [13058][512]
    unsigned short* Qt  = U + 13107200;             // [51200][96] (reuse after key path)
    unsigned short* Xq  = U + 19792896;             // [51458][96]
    unsigned short* Kt  = U + 24732864;             // [12800][96]
    unsigned short* Wk1 = U + 25961664;             // 3*1024*512
    unsigned short* Wk2 = U + 27534528;             // 128*1024
    unsigned short* Wq1 = U + 27665600;             // 3*256*96
    unsigned short* Wq2 = U + 27739328;             // 128*160
    unsigned short* Wq3 = U + 27759808;             // 128*96
    float*          k2s = (float*)(U + 27772096);   // 12800 f32

    float* out_attn = (float*)d_out;
    float* out_lp   = out_attn + (size_t)32 * 1600 * 400;

    // 1) all prep
    prep_all<<<NKB + NQB + NFB, dim3(256), 0, stream>>>(
        keys, queries, kw1, kw2, qw1, qw2, qw3,
        Xk, Xq, Wk1, Wk2, Wq1, Wq2, Wq3);

    // 2) both 3-tap convs (key 408 + q 402, balanced per XCD)
    conv1_both<<<810, dim3(512), 0, stream>>>(
        Wk1, Xk, kb1, K1t, Wq1, Xq, qb1, Q1t);

    // 3) key conv2 (+k2) || q conv2+conv3 fused
    conv2_both<<<500, dim3(256), 0, stream>>>(
        Wk2, K1t, kb2, Kt, k2s, Wq2, Wq3, qb2, qb3, Q1t, Qt);

    // 4) fused attention + softmaxes (float4 I/O)
    attn_v2<<<dim3(50, 32), dim3(512), 0, stream>>>(
        Kt, Qt, k2s, prior, mask, out_attn, out_lp);
}